// Round 13
// baseline (395.462 us; speedup 1.0000x reference)
//
#include <hip/hip_runtime.h>

// ---------------------------------------------------------------------------
// GraphElementNetwork forward, bucketed path v12:
//  - edge passes now 128-thread (2-wave) blocks @ G=16: doubles per-thread
//    work (passB: 2 full 8-edge pipelined chunks) AND raises per-CU wave
//    packing cap to 100% (16 blocks x 2 waves; LDS 6KB x 16 = 98KB ok).
//    r10-r12 plateau: 256-thr blocks gave 1-chunk slices + 36% occupancy.
//  - chist/scatter stay 1024-thr (r10 win); shift=9 (r7); weights as
//    wave-uniform scalar loads (r6); packed fv2 MLP + prefetch (r8).
// ---------------------------------------------------------------------------

#define NHB 256   // histogram / scatter blocks

typedef int   iv4 __attribute__((ext_vector_type(4)));
typedef float fv4 __attribute__((ext_vector_type(4)));
typedef float fv2 __attribute__((ext_vector_type(2)));

#if __has_builtin(__builtin_elementwise_fma)
#define FMA2(a, b, c) __builtin_elementwise_fma((a), (b), (c))
#else
static __device__ __forceinline__ fv2 FMA2(fv2 a, fv2 b, fv2 c) {
    fv2 r; r.x = fmaf(a.x, b.x, c.x); r.y = fmaf(a.y, b.y, c.y); return r;
}
#endif
#if __has_builtin(__builtin_elementwise_max)
#define MAX2(a, b) __builtin_elementwise_max((a), (b))
#else
static __device__ __forceinline__ fv2 MAX2(fv2 a, fv2 b) {
    fv2 r; r.x = fmaxf(a.x, b.x); r.y = fmaxf(a.y, b.y); return r;
}
#endif

// ============================ bucketing ====================================

__global__ void __launch_bounds__(1024) k_chist(
    const int* __restrict__ DST, int* __restrict__ hist,
    int e, int nbkt, int shift, int epb)
{
    __shared__ int lh[512];
    for (int c = threadIdx.x; c < nbkt; c += blockDim.x) lh[c] = 0;
    __syncthreads();
    int b = blockIdx.x;
    int i0 = b * epb, i1 = min(i0 + epb, e);
    int nq = (i1 > i0) ? ((i1 - i0) >> 2) : 0;
    const iv4* D4 = reinterpret_cast<const iv4*>(DST + i0);
    for (int q = threadIdx.x; q < nq; q += blockDim.x) {
        iv4 d = D4[q];
        atomicAdd(&lh[d.x >> shift], 1);
        atomicAdd(&lh[d.y >> shift], 1);
        atomicAdd(&lh[d.z >> shift], 1);
        atomicAdd(&lh[d.w >> shift], 1);
    }
    for (int i = i0 + 4 * nq + threadIdx.x; i < i1; i += blockDim.x)
        atomicAdd(&lh[DST[i] >> shift], 1);
    __syncthreads();
    for (int c = threadIdx.x; c < nbkt; c += blockDim.x)
        hist[(size_t)c * NHB + b] = lh[c];
}

__global__ void __launch_bounds__(256) k_scanA(
    int* __restrict__ hist, int* __restrict__ bktCnt)
{
    int c = blockIdx.x;
    int* row = hist + (size_t)c * NHB;
    __shared__ int part[256];
    int t = threadIdx.x;
    int v = row[t];
    part[t] = v;
    __syncthreads();
    for (int off = 1; off < 256; off <<= 1) {
        int x = 0;
        if (t >= off) x = part[t - off];
        __syncthreads();
        part[t] += x;
        __syncthreads();
    }
    if (t == 255) bktCnt[c] = part[255];
    row[t] = part[t] - v;
}

__global__ void __launch_bounds__(256) k_scanB(
    const int* __restrict__ bktCnt, int* __restrict__ base, int nbkt, int e)
{
    __shared__ int part[256];
    int t = threadIdx.x;
    int v[4];
    int sum = 0;
    #pragma unroll
    for (int u = 0; u < 4; ++u) {
        int idx = t * 4 + u;
        v[u] = (idx < nbkt) ? bktCnt[idx] : 0;
        sum += v[u];
    }
    part[t] = sum;
    __syncthreads();
    for (int off = 1; off < 256; off <<= 1) {
        int x = 0;
        if (t >= off) x = part[t - off];
        __syncthreads();
        part[t] += x;
        __syncthreads();
    }
    int run = (t == 0) ? 0 : part[t - 1];
    #pragma unroll
    for (int u = 0; u < 4; ++u) {
        int idx = t * 4 + u;
        if (idx < nbkt) base[idx] = run;
        run += v[u];
    }
    if (t == 0) base[nbkt] = e;
}

__global__ void __launch_bounds__(1024) k_scatter(
    const int* __restrict__ DST, const int* __restrict__ SRC,
    const float* __restrict__ DIST, const float* __restrict__ EF,
    const int* __restrict__ hist, const int* __restrict__ base,
    float2* __restrict__ payA, float* __restrict__ ef_s,
    int e, int nbkt, int shift, int epb)
{
    __shared__ int loff[512];
    int b = blockIdx.x;
    for (int c = threadIdx.x; c < nbkt; c += blockDim.x)
        loff[c] = base[c] + hist[(size_t)c * NHB + b];
    __syncthreads();
    int i0 = b * epb, i1 = min(i0 + epb, e);
    if (i0 >= i1) return;
    int mask = (1 << shift) - 1;
    int nq = (i1 - i0) >> 2;
    const iv4* D4 = reinterpret_cast<const iv4*>(DST + i0);
    const iv4* S4 = reinterpret_cast<const iv4*>(SRC + i0);
    const fv4* T4 = reinterpret_cast<const fv4*>(DIST + i0);
    const fv4* F4 = reinterpret_cast<const fv4*>(EF + i0);
    for (int q = threadIdx.x; q < nq; q += blockDim.x) {
        iv4 dv = __builtin_nontemporal_load(D4 + q);
        iv4 sv = __builtin_nontemporal_load(S4 + q);
        fv4 tv = __builtin_nontemporal_load(T4 + q);
        fv4 fv = __builtin_nontemporal_load(F4 + q);
        #pragma unroll
        for (int u = 0; u < 4; ++u) {
            int d = dv[u];
            int c = d >> shift;
            int pos = atomicAdd(&loff[c], 1);
            int sd = (sv[u] << shift) | (d & mask);
            payA[pos] = make_float2(__int_as_float(sd), tv[u]);
            ef_s[pos] = fv[u];
        }
    }
    for (int i = i0 + 4 * nq + threadIdx.x; i < i1; i += blockDim.x) {
        int d = DST[i];
        int c = d >> shift;
        int pos = atomicAdd(&loff[c], 1);
        int sd = (SRC[i] << shift) | (d & mask);
        payA[pos] = make_float2(__int_as_float(sd), DIST[i]);
        ef_s[pos] = EF[i];
    }
}

// ============================ node encoder =================================

__global__ void __launch_bounds__(256) k_enc(
    const float* __restrict__ X, const float* __restrict__ W1,
    const float* __restrict__ B1, const float* __restrict__ W2,
    const float* __restrict__ B2, float* __restrict__ H0, int n)
{
    __shared__ float4 w1s[2048];
    for (int t = threadIdx.x; t < 2048; t += blockDim.x)
        w1s[t] = reinterpret_cast<const float4*>(W1)[t];
    __syncthreads();

    int i = blockIdx.x * blockDim.x + threadIdx.x;
    if (i >= n) return;

    const float4* xp = reinterpret_cast<const float4*>(X) + (size_t)i * 32;

    float acc[64];
    #pragma unroll
    for (int j = 0; j < 64; ++j) acc[j] = B1[j];

    for (int k4 = 0; k4 < 32; ++k4) {
        float4 xv = xp[k4];
        #pragma unroll
        for (int kk = 0; kk < 4; ++kk) {
            float x = (&xv.x)[kk];
            const float4* wrow = &w1s[(k4 * 4 + kk) * 16];
            #pragma unroll
            for (int j4 = 0; j4 < 16; ++j4) {
                float4 w = wrow[j4];
                acc[j4*4+0] = fmaf(x, w.x, acc[j4*4+0]);
                acc[j4*4+1] = fmaf(x, w.y, acc[j4*4+1]);
                acc[j4*4+2] = fmaf(x, w.z, acc[j4*4+2]);
                acc[j4*4+3] = fmaf(x, w.w, acc[j4*4+3]);
            }
        }
    }
    float o = B2[0];
    #pragma unroll
    for (int j = 0; j < 64; ++j)
        o = fmaf(fmaxf(acc[j], 0.f), W2[j], o);
    H0[i] = fmaxf(o, 0.f);
}

// ==================== bucketed edge passes (G-split) =======================
// partial layout: p[((c*G + g) << shift) + t]
// 128-thread (2-wave) blocks: 16 blocks/CU resident (32 waves = 100% cap)
// AND 2x per-thread work so the prefetch pipeline has >1 iteration.

__global__ void __launch_bounds__(128) k_passA(
    const float2* __restrict__ payA, const float* __restrict__ H0,
    const int* __restrict__ base,
    float* __restrict__ pSum, float* __restrict__ pNum, int shift, int G)
{
    __shared__ float lsum[512], lnum[512];
    int c = blockIdx.x / G, g = blockIdx.x % G;
    int bw = 1 << shift, mask = bw - 1;
    for (int t = threadIdx.x; t < bw; t += blockDim.x) { lsum[t] = 0.f; lnum[t] = 0.f; }
    __syncthreads();
    int b0 = base[c], len = base[c + 1] - b0;
    int i0 = b0 + (int)(((long long)len * g) / G);
    int i1 = b0 + (int)(((long long)len * (g + 1)) / G);
    const int T = blockDim.x;
    for (int i = i0 + (int)threadIdx.x; i < i1; i += 2 * T) {
        int jb = i + T;
        fv2 p0 = __builtin_nontemporal_load(
            reinterpret_cast<const fv2*>(payA) + i);
        fv2 p1 = {0.f, 0.f};
        bool vb = jb < i1;
        if (vb) p1 = __builtin_nontemporal_load(
                    reinterpret_cast<const fv2*>(payA) + jb);
        int sd0 = __float_as_int(p0.x);
        int sd1 = __float_as_int(p1.x);
        float h0a = H0[sd0 >> shift];
        float h0b = vb ? H0[sd1 >> shift] : 0.f;
        float e0 = __expf(p0.y);
        float e1 = __expf(p1.y);
        atomicAdd(&lsum[sd0 & mask], e0);
        atomicAdd(&lnum[sd0 & mask], e0 * h0a);
        if (vb) {
            atomicAdd(&lsum[sd1 & mask], e1);
            atomicAdd(&lnum[sd1 & mask], e1 * h0b);
        }
    }
    __syncthreads();
    size_t po = (size_t)blockIdx.x << shift;
    for (int t = threadIdx.x; t < bw; t += blockDim.x) {
        pSum[po + t] = lsum[t];
        pNum[po + t] = lnum[t];
    }
}

__global__ void __launch_bounds__(256) k_finA(
    const float* __restrict__ pSum, const float* __restrict__ pNum,
    float* __restrict__ H1, int shift, int n, int G)
{
    int d = blockIdx.x * blockDim.x + threadIdx.x;
    if (d >= n) return;
    int c = d >> shift, t = d & ((1 << shift) - 1);
    size_t b = (size_t)c * G << shift;
    int bw = 1 << shift;
    float s = 0.f, m = 0.f;
    for (int g = 0; g < G; ++g) {
        s += pSum[b + (size_t)g * bw + t];
        m += pNum[b + (size_t)g * bw + t];
    }
    H1[d] = (s != 0.f) ? m / s : 0.f;
}

// passB main: edge MLP -> e2 (overwrites ef_s) + partial agg/s2.
// 8-edge chunks; per-edge packed MLP; 128-thread blocks -> 2 chunks/thread.
__global__ void __launch_bounds__(128) k_passB(
    const float2* __restrict__ payA, float* __restrict__ ef_s,
    const float* __restrict__ H1,
    const float* __restrict__ W1, const float* __restrict__ B1,
    const float* __restrict__ W2, const float* __restrict__ B2,
    const int* __restrict__ base,
    float* __restrict__ pAgg, float* __restrict__ pS2, int shift, int n, int G)
{
    __shared__ float h1loc[512], lagg[512], ls2[512];
    const fv2 ZERO2 = {0.f, 0.f};
    int bw = 1 << shift, mask = bw - 1;
    int c = blockIdx.x / G, g = blockIdx.x % G;
    int d0 = c << shift;
    for (int t = threadIdx.x; t < bw; t += blockDim.x) {
        int d = d0 + t;
        h1loc[t] = (d < n) ? H1[d] : 0.f;
        lagg[t] = 0.f;
        ls2[t] = 0.f;
    }
    __syncthreads();
    const float b2 = B2[0];
    int b0 = base[c], len = base[c + 1] - b0;
    int i0 = b0 + (int)(((long long)len * g) / G);
    int i1 = b0 + (int)(((long long)len * (g + 1)) / G);
    const int T = blockDim.x;

    int i = i0 + (int)threadIdx.x;
    fv2 pa[8]; float xf[8];
    #pragma unroll
    for (int u = 0; u < 8; ++u) {
        int j = i + u * T;
        pa[u] = ZERO2; xf[u] = 0.f;
        if (j < i1) {
            pa[u] = __builtin_nontemporal_load(
                reinterpret_cast<const fv2*>(payA) + j);
            xf[u] = __builtin_nontemporal_load(ef_s + j);
        }
    }
    while (i < i1) {
        int inext = i + 8 * T;
        // prefetch next chunk BEFORE this chunk's compute/store phase
        fv2 pb[8]; float xg[8];
        #pragma unroll
        for (int u = 0; u < 8; ++u) {
            int j = inext + u * T;
            pb[u] = ZERO2; xg[u] = 0.f;
            if (j < i1) {
                pb[u] = __builtin_nontemporal_load(
                    reinterpret_cast<const fv2*>(payA) + j);
                xg[u] = __builtin_nontemporal_load(ef_s + j);
            }
        }
        // all 8 gathers issued up front (memory-level parallelism)
        float hs[8]; int lo[8];
        #pragma unroll
        for (int u = 0; u < 8; ++u) {
            int sd = __float_as_int(pa[u].x);
            lo[u] = sd & mask;
            hs[u] = H1[sd >> shift];
        }
        // per-edge packed MLP: only one edge's broadcast pairs live at a time
        #pragma unroll
        for (int u = 0; u < 8; ++u) {
            int j = i + u * T;
            if (j < i1) {
                float hd = h1loc[lo[u]];
                fv2 xv; xv.x = xf[u]; xv.y = xf[u];
                fv2 hv; hv.x = hs[u]; hv.y = hs[u];
                fv2 dv; dv.x = hd;    dv.y = hd;
                fv2 o2 = ZERO2;
                #pragma unroll 8
                for (int jj = 0; jj < 64; jj += 2) {
                    fv2 aj = *reinterpret_cast<const fv2*>(W1 + jj);
                    fv2 bj = *reinterpret_cast<const fv2*>(W1 + 64 + jj);
                    fv2 cj = *reinterpret_cast<const fv2*>(W1 + 128 + jj);
                    fv2 dj = *reinterpret_cast<const fv2*>(B1 + jj);
                    fv2 vj = *reinterpret_cast<const fv2*>(W2 + jj);
                    fv2 t = FMA2(xv, aj, FMA2(hv, bj, FMA2(dv, cj, dj)));
                    t = MAX2(t, ZERO2);
                    o2 = FMA2(t, vj, o2);
                }
                float eh = fmaxf(o2.x + o2.y + b2, 0.f);
                float ex = __expf(eh);
                ef_s[j] = ex;
                atomicAdd(&lagg[lo[u]], eh);
                atomicAdd(&ls2[lo[u]], ex);
            }
        }
        i = inext;
        #pragma unroll
        for (int u = 0; u < 8; ++u) { pa[u] = pb[u]; xf[u] = xg[u]; }
    }
    __syncthreads();
    size_t po = (size_t)blockIdx.x << shift;
    for (int t = threadIdx.x; t < bw; t += blockDim.x) {
        pAgg[po + t] = lagg[t];
        pS2[po + t] = ls2[t];
    }
}

// finB: sum partials; H2 = nuMLP(agg, h1); S2
__global__ void __launch_bounds__(256) k_finB(
    const float* __restrict__ pAgg, const float* __restrict__ pS2,
    const float* __restrict__ H1,
    const float* __restrict__ NW1, const float* __restrict__ NB1,
    const float* __restrict__ NW2, const float* __restrict__ NB2,
    float* __restrict__ H2, float* __restrict__ S2, int shift, int n, int G)
{
    int d = blockIdx.x * blockDim.x + threadIdx.x;
    if (d >= n) return;
    int c = d >> shift, t = d & ((1 << shift) - 1);
    size_t b = (size_t)c * G << shift;
    int bw = 1 << shift;
    float agg = 0.f, s2 = 0.f;
    for (int g = 0; g < G; ++g) {
        agg += pAgg[b + (size_t)g * bw + t];
        s2  += pS2[b + (size_t)g * bw + t];
    }
    float xh = H1[d];
    float o = NB2[0];
    #pragma unroll 4
    for (int j = 0; j < 64; ++j) {
        float a = fmaf(agg, NW1[j], fmaf(xh, NW1[64 + j], NB1[j]));
        o = fmaf(fmaxf(a, 0.f), NW2[j], o);
    }
    H2[d] = fmaxf(o, 0.f);
    S2[d] = s2;
}

// passC main: partial num2 (2-edge ILP)
__global__ void __launch_bounds__(128) k_passC(
    const float2* __restrict__ payA, const float* __restrict__ e2_s,
    const float* __restrict__ H2, const int* __restrict__ base,
    float* __restrict__ pNum, int shift, int G)
{
    __shared__ float lnum[512];
    int c = blockIdx.x / G, g = blockIdx.x % G;
    int bw = 1 << shift, mask = bw - 1;
    for (int t = threadIdx.x; t < bw; t += blockDim.x) lnum[t] = 0.f;
    __syncthreads();
    int b0 = base[c], len = base[c + 1] - b0;
    int i0 = b0 + (int)(((long long)len * g) / G);
    int i1 = b0 + (int)(((long long)len * (g + 1)) / G);
    const int T = blockDim.x;
    for (int i = i0 + (int)threadIdx.x; i < i1; i += 2 * T) {
        int jb = i + T;
        bool vb = jb < i1;
        fv2 p0 = __builtin_nontemporal_load(
            reinterpret_cast<const fv2*>(payA) + i);
        float e0 = __builtin_nontemporal_load(e2_s + i);
        fv2 p1 = {0.f, 0.f};
        float e1 = 0.f;
        if (vb) {
            p1 = __builtin_nontemporal_load(
                reinterpret_cast<const fv2*>(payA) + jb);
            e1 = __builtin_nontemporal_load(e2_s + jb);
        }
        int sd0 = __float_as_int(p0.x);
        int sd1 = __float_as_int(p1.x);
        float m0 = e0 * H2[sd0 >> shift];
        float m1 = vb ? e1 * H2[sd1 >> shift] : 0.f;
        atomicAdd(&lnum[sd0 & mask], m0);
        if (vb) atomicAdd(&lnum[sd1 & mask], m1);
    }
    __syncthreads();
    size_t po = (size_t)blockIdx.x << shift;
    for (int t = threadIdx.x; t < bw; t += blockDim.x)
        pNum[po + t] = lnum[t];
}

// finC: sum partials; OUT = decMLP(num2/s2)
__global__ void __launch_bounds__(256) k_finC(
    const float* __restrict__ pNum, const float* __restrict__ S2,
    const float* __restrict__ W1, const float* __restrict__ B1,
    const float* __restrict__ W2, const float* __restrict__ B2,
    float* __restrict__ OUT, int shift, int n, int G)
{
    int d = blockIdx.x * blockDim.x + threadIdx.x;
    if (d >= n) return;
    int c = d >> shift, t = d & ((1 << shift) - 1);
    size_t b = (size_t)c * G << shift;
    int bw = 1 << shift;
    float m = 0.f;
    for (int g = 0; g < G; ++g) m += pNum[b + (size_t)g * bw + t];
    float s = S2[d];
    float x = (s != 0.f) ? m / s : 0.f;
    float o = B2[0];
    #pragma unroll 4
    for (int j = 0; j < 64; ++j) {
        float a = fmaf(x, W1[j], B1[j]);
        o = fmaf(fmaxf(a, 0.f), W2[j], o);
    }
    OUT[d] = fmaxf(o, 0.f);
}

// ===================== fallback (atomic path) ==============================

__device__ __forceinline__ void atomAddF(float* p, float v) { unsafeAtomicAdd(p, v); }

__global__ void k_zero(float* __restrict__ p, int n) {
    int i = blockIdx.x * blockDim.x + threadIdx.x;
    if (i < n) p[i] = 0.f;
}

__global__ void __launch_bounds__(256) k_agg1(
    const float* __restrict__ DIST, const int* __restrict__ SRC,
    const int* __restrict__ DST, const float* __restrict__ H0,
    float* __restrict__ S1, float* __restrict__ NUM1, int e)
{
    int i = blockIdx.x * blockDim.x + threadIdx.x;
    if (i >= e) return;
    float ev = __expf(DIST[i]);
    atomAddF(&S1[DST[i]], ev);
    atomAddF(&NUM1[DST[i]], ev * H0[SRC[i]]);
}

__global__ void k_div(const float* __restrict__ NUM, const float* __restrict__ S,
                      float* __restrict__ H, int n) {
    int i = blockIdx.x * blockDim.x + threadIdx.x;
    if (i < n) {
        float s = S[i];
        H[i] = (s != 0.f) ? NUM[i] / s : 0.f;
    }
}

__global__ void __launch_bounds__(256) k_edgeF(
    const float* __restrict__ EF, const int* __restrict__ SRC,
    const int* __restrict__ DST, const float* __restrict__ H1,
    const float* __restrict__ W1, const float* __restrict__ B1,
    const float* __restrict__ W2, const float* __restrict__ B2,
    float* __restrict__ E2, float* __restrict__ AGG, float* __restrict__ S2, int e)
{
    int i = blockIdx.x * blockDim.x + threadIdx.x;
    if (i >= e) return;
    float x0 = EF[i];
    int s = SRC[i], d = DST[i];
    float h_s = H1[s], h_d = H1[d];
    float o = B2[0];
    for (int j = 0; j < 64; ++j) {
        float aj = fmaf(x0, W1[j], fmaf(h_s, W1[64+j], fmaf(h_d, W1[128+j], B1[j])));
        o = fmaf(fmaxf(aj, 0.f), W2[j], o);
    }
    float eh = fmaxf(o, 0.f);
    float ex = __expf(eh);
    E2[i] = ex;
    atomAddF(&AGG[d], eh);
    atomAddF(&S2[d], ex);
}

__global__ void k_nu(const float* __restrict__ AGG, const float* __restrict__ H1,
                     const float* __restrict__ W1, const float* __restrict__ B1,
                     const float* __restrict__ W2, const float* __restrict__ B2,
                     float* __restrict__ H2, int n)
{
    int i = blockIdx.x * blockDim.x + threadIdx.x;
    if (i >= n) return;
    float x0 = AGG[i], x1 = H1[i];
    float o = B2[0];
    #pragma unroll
    for (int j = 0; j < 64; ++j) {
        float a = fmaf(x0, W1[j], fmaf(x1, W1[64 + j], B1[j]));
        o = fmaf(fmaxf(a, 0.f), W2[j], o);
    }
    H2[i] = fmaxf(o, 0.f);
}

__global__ void __launch_bounds__(256) k_agg2F(
    const float* __restrict__ E2, const int* __restrict__ SRC,
    const int* __restrict__ DST, const float* __restrict__ H2,
    float* __restrict__ NUM2, int e)
{
    int i = blockIdx.x * blockDim.x + threadIdx.x;
    if (i >= e) return;
    atomAddF(&NUM2[DST[i]], E2[i] * H2[SRC[i]]);
}

__global__ void k_final(const float* __restrict__ NUM2, const float* __restrict__ S2,
                        const float* __restrict__ W1, const float* __restrict__ B1,
                        const float* __restrict__ W2, const float* __restrict__ B2,
                        float* __restrict__ OUT, int n)
{
    int i = blockIdx.x * blockDim.x + threadIdx.x;
    if (i >= n) return;
    float s = S2[i];
    float x = (s != 0.f) ? NUM2[i] / s : 0.f;
    float o = B2[0];
    #pragma unroll
    for (int j = 0; j < 64; ++j) {
        float a = fmaf(x, W1[j], B1[j]);
        o = fmaf(fmaxf(a, 0.f), W2[j], o);
    }
    OUT[i] = fmaxf(o, 0.f);
}

// ============================ launch =======================================

extern "C" void kernel_launch(void* const* d_in, const int* in_sizes, int n_in,
                              void* d_out, int out_size, void* d_ws, size_t ws_size,
                              hipStream_t stream)
{
    const float* node_feat = (const float*)d_in[0];
    const float* edge_feat = (const float*)d_in[1];
    const float* edge_dist = (const float*)d_in[2];
    const int*   src       = (const int*)d_in[3];
    const int*   dst       = (const int*)d_in[4];
    const float* enc_w1 = (const float*)d_in[5];
    const float* enc_b1 = (const float*)d_in[6];
    const float* enc_w2 = (const float*)d_in[7];
    const float* enc_b2 = (const float*)d_in[8];
    const float* nu_w1  = (const float*)d_in[9];
    const float* nu_b1  = (const float*)d_in[10];
    const float* nu_w2  = (const float*)d_in[11];
    const float* nu_b2  = (const float*)d_in[12];
    const float* eu_w1  = (const float*)d_in[13];
    const float* eu_b1  = (const float*)d_in[14];
    const float* eu_w2  = (const float*)d_in[15];
    const float* eu_b2  = (const float*)d_in[16];
    const float* dec_w1 = (const float*)d_in[17];
    const float* dec_b1 = (const float*)d_in[18];
    const float* dec_w2 = (const float*)d_in[19];
    const float* dec_b2 = (const float*)d_in[20];

    const int n = in_sizes[0] / 128;
    const int e = in_sizes[1];
    const int B = 256;

    int shift = 9;
    while ((((n + (1 << shift) - 1) >> shift) > 512) && shift < 12) shift++;
    const int nbkt = (n + (1 << shift) - 1) >> shift;
    int epb = (e + NHB - 1) / NHB;
    epb = (epb + 3) & ~3;

    // ws layout (4B words): h0,h1,h2,s2 [4n] | base[nbkt+1] bktCnt[nbkt]
    // hist[nbkt*NHB] | pad8 | payA[2e] | ef_s[e] | pP0 | pP1
    float* ws = (float*)d_ws;
    size_t w = (size_t)4 * n;
    int* base   = (int*)(ws + w); w += nbkt + 1;
    int* bktCnt = (int*)(ws + w); w += nbkt;
    int* hist   = (int*)(ws + w); w += (size_t)nbkt * NHB;
    w = (w + 1) & ~(size_t)1;
    float2* payA = (float2*)(ws + w); w += (size_t)2 * e;
    float* ef_s  = ws + w; w += e;

    // pick largest G in {16,8,4,2,1} whose partial arrays fit the workspace
    int G = 16;
    size_t psz;
    size_t need;
    for (;;) {
        psz = ((size_t)nbkt * G) << shift;
        need = (w + 2 * psz) * 4;
        if (need <= ws_size || G == 1) break;
        G >>= 1;
    }
    float* pP0 = ws + w;
    float* pP1 = ws + w + psz;

    float* h0 = ws;
    float* h1 = ws + (size_t)1 * n;
    float* h2 = ws + (size_t)2 * n;
    float* s2 = ws + (size_t)3 * n;

    if (ws_size >= need && nbkt <= 512 && (1 << shift) <= 512 &&
        ((size_t)n << shift) < (1u << 30)) {
        const int gE = nbkt * G;
        hipLaunchKernelGGL(k_chist, dim3(NHB), dim3(1024), 0, stream,
                           dst, hist, e, nbkt, shift, epb);
        hipLaunchKernelGGL(k_scanA, dim3(nbkt), dim3(B), 0, stream, hist, bktCnt);
        hipLaunchKernelGGL(k_scanB, dim3(1), dim3(B), 0, stream, bktCnt, base, nbkt, e);
        hipLaunchKernelGGL(k_scatter, dim3(NHB), dim3(1024), 0, stream,
                           dst, src, edge_dist, edge_feat, hist, base,
                           payA, ef_s, e, nbkt, shift, epb);
        hipLaunchKernelGGL(k_enc, dim3((n + B - 1) / B), dim3(B), 0, stream,
                           node_feat, enc_w1, enc_b1, enc_w2, enc_b2, h0, n);
        hipLaunchKernelGGL(k_passA, dim3(gE), dim3(128), 0, stream,
                           payA, h0, base, pP0, pP1, shift, G);
        hipLaunchKernelGGL(k_finA, dim3((n + B - 1) / B), dim3(B), 0, stream,
                           pP0, pP1, h1, shift, n, G);
        hipLaunchKernelGGL(k_passB, dim3(gE), dim3(128), 0, stream,
                           payA, ef_s, h1, eu_w1, eu_b1, eu_w2, eu_b2, base,
                           pP0, pP1, shift, n, G);
        hipLaunchKernelGGL(k_finB, dim3((n + B - 1) / B), dim3(B), 0, stream,
                           pP0, pP1, h1, nu_w1, nu_b1, nu_w2, nu_b2, h2, s2,
                           shift, n, G);
        hipLaunchKernelGGL(k_passC, dim3(gE), dim3(128), 0, stream,
                           payA, ef_s /*e2*/, h2, base, pP0, shift, G);
        hipLaunchKernelGGL(k_finC, dim3((n + B - 1) / B), dim3(B), 0, stream,
                           pP0, s2, dec_w1, dec_b1, dec_w2, dec_b2,
                           (float*)d_out, shift, n, G);
    } else {
        // fallback: atomic path (needs 8n + e floats)
        float* agg  = ws + (size_t)2 * n;
        float* s1   = ws + (size_t)4 * n;
        float* num1 = ws + (size_t)5 * n;
        float* num2 = ws + (size_t)6 * n;
        float* h2f  = ws + (size_t)7 * n;
        float* e2   = ws + (size_t)8 * n;
        hipLaunchKernelGGL(k_zero, dim3((5 * n + B - 1) / B), dim3(B), 0, stream,
                           agg, 5 * n);
        hipLaunchKernelGGL(k_enc, dim3((n + B - 1) / B), dim3(B), 0, stream,
                           node_feat, enc_w1, enc_b1, enc_w2, enc_b2, h0, n);
        hipLaunchKernelGGL(k_agg1, dim3((e + B - 1) / B), dim3(B), 0, stream,
                           edge_dist, src, dst, h0, s1, num1, e);
        hipLaunchKernelGGL(k_div, dim3((n + B - 1) / B), dim3(B), 0, stream,
                           num1, s1, h1, n);
        hipLaunchKernelGGL(k_edgeF, dim3((e + B - 1) / B), dim3(B), 0, stream,
                           edge_feat, src, dst, h1, eu_w1, eu_b1, eu_w2, eu_b2,
                           e2, agg, s2, e);
        hipLaunchKernelGGL(k_nu, dim3((n + B - 1) / B), dim3(B), 0, stream,
                           agg, h1, nu_w1, nu_b1, nu_w2, nu_b2, h2f, n);
        hipLaunchKernelGGL(k_agg2F, dim3((e + B - 1) / B), dim3(B), 0, stream,
                           e2, src, dst, h2f, num2, e);
        hipLaunchKernelGGL(k_final, dim3((n + B - 1) / B), dim3(B), 0, stream,
                           num2, s2, dec_w1, dec_b1, dec_w2, dec_b2, (float*)d_out, n);
    }
}

// Round 14
// 395.137 us; speedup vs baseline: 1.0008x; 1.0008x over previous
//
#include <hip/hip_runtime.h>

// ---------------------------------------------------------------------------
// GraphElementNetwork forward, bucketed path v13:
//  - shift=8 (391 buckets, 256-wide bins): halves per-block zero/writeback
//    and finalize costs vs shift=9 (r13 analysis: fixed cost ~= payload at
//    800-edge slices). More buckets -> more blocks at same slice length.
//  - passB: NO h1loc stage; hd read directly from H1 (1KB window, L1-hot).
//  - passes 256-thr, 4-edge chunk + prefetch (r10's best passB structure).
//  - chist/scatter 1024-thr + nontemporal (r9/r7); weights scalar (r6).
// ---------------------------------------------------------------------------

#define NHB 256   // histogram / scatter blocks

typedef int   iv4 __attribute__((ext_vector_type(4)));
typedef float fv4 __attribute__((ext_vector_type(4)));
typedef float fv2 __attribute__((ext_vector_type(2)));

#if __has_builtin(__builtin_elementwise_fma)
#define FMA2(a, b, c) __builtin_elementwise_fma((a), (b), (c))
#else
static __device__ __forceinline__ fv2 FMA2(fv2 a, fv2 b, fv2 c) {
    fv2 r; r.x = fmaf(a.x, b.x, c.x); r.y = fmaf(a.y, b.y, c.y); return r;
}
#endif
#if __has_builtin(__builtin_elementwise_max)
#define MAX2(a, b) __builtin_elementwise_max((a), (b))
#else
static __device__ __forceinline__ fv2 MAX2(fv2 a, fv2 b) {
    fv2 r; r.x = fmaxf(a.x, b.x); r.y = fmaxf(a.y, b.y); return r;
}
#endif

// ============================ bucketing ====================================

__global__ void __launch_bounds__(1024) k_chist(
    const int* __restrict__ DST, int* __restrict__ hist,
    int e, int nbkt, int shift, int epb)
{
    __shared__ int lh[512];
    for (int c = threadIdx.x; c < nbkt; c += blockDim.x) lh[c] = 0;
    __syncthreads();
    int b = blockIdx.x;
    int i0 = b * epb, i1 = min(i0 + epb, e);
    int nq = (i1 > i0) ? ((i1 - i0) >> 2) : 0;
    const iv4* D4 = reinterpret_cast<const iv4*>(DST + i0);
    for (int q = threadIdx.x; q < nq; q += blockDim.x) {
        iv4 d = D4[q];
        atomicAdd(&lh[d.x >> shift], 1);
        atomicAdd(&lh[d.y >> shift], 1);
        atomicAdd(&lh[d.z >> shift], 1);
        atomicAdd(&lh[d.w >> shift], 1);
    }
    for (int i = i0 + 4 * nq + threadIdx.x; i < i1; i += blockDim.x)
        atomicAdd(&lh[DST[i] >> shift], 1);
    __syncthreads();
    for (int c = threadIdx.x; c < nbkt; c += blockDim.x)
        hist[(size_t)c * NHB + b] = lh[c];
}

__global__ void __launch_bounds__(256) k_scanA(
    int* __restrict__ hist, int* __restrict__ bktCnt)
{
    int c = blockIdx.x;
    int* row = hist + (size_t)c * NHB;
    __shared__ int part[256];
    int t = threadIdx.x;
    int v = row[t];
    part[t] = v;
    __syncthreads();
    for (int off = 1; off < 256; off <<= 1) {
        int x = 0;
        if (t >= off) x = part[t - off];
        __syncthreads();
        part[t] += x;
        __syncthreads();
    }
    if (t == 255) bktCnt[c] = part[255];
    row[t] = part[t] - v;
}

__global__ void __launch_bounds__(256) k_scanB(
    const int* __restrict__ bktCnt, int* __restrict__ base, int nbkt, int e)
{
    __shared__ int part[256];
    int t = threadIdx.x;
    int v[4];
    int sum = 0;
    #pragma unroll
    for (int u = 0; u < 4; ++u) {
        int idx = t * 4 + u;
        v[u] = (idx < nbkt) ? bktCnt[idx] : 0;
        sum += v[u];
    }
    part[t] = sum;
    __syncthreads();
    for (int off = 1; off < 256; off <<= 1) {
        int x = 0;
        if (t >= off) x = part[t - off];
        __syncthreads();
        part[t] += x;
        __syncthreads();
    }
    int run = (t == 0) ? 0 : part[t - 1];
    #pragma unroll
    for (int u = 0; u < 4; ++u) {
        int idx = t * 4 + u;
        if (idx < nbkt) base[idx] = run;
        run += v[u];
    }
    if (t == 0) base[nbkt] = e;
}

__global__ void __launch_bounds__(1024) k_scatter(
    const int* __restrict__ DST, const int* __restrict__ SRC,
    const float* __restrict__ DIST, const float* __restrict__ EF,
    const int* __restrict__ hist, const int* __restrict__ base,
    float2* __restrict__ payA, float* __restrict__ ef_s,
    int e, int nbkt, int shift, int epb)
{
    __shared__ int loff[512];
    int b = blockIdx.x;
    for (int c = threadIdx.x; c < nbkt; c += blockDim.x)
        loff[c] = base[c] + hist[(size_t)c * NHB + b];
    __syncthreads();
    int i0 = b * epb, i1 = min(i0 + epb, e);
    if (i0 >= i1) return;
    int mask = (1 << shift) - 1;
    int nq = (i1 - i0) >> 2;
    const iv4* D4 = reinterpret_cast<const iv4*>(DST + i0);
    const iv4* S4 = reinterpret_cast<const iv4*>(SRC + i0);
    const fv4* T4 = reinterpret_cast<const fv4*>(DIST + i0);
    const fv4* F4 = reinterpret_cast<const fv4*>(EF + i0);
    for (int q = threadIdx.x; q < nq; q += blockDim.x) {
        iv4 dv = __builtin_nontemporal_load(D4 + q);
        iv4 sv = __builtin_nontemporal_load(S4 + q);
        fv4 tv = __builtin_nontemporal_load(T4 + q);
        fv4 fv = __builtin_nontemporal_load(F4 + q);
        #pragma unroll
        for (int u = 0; u < 4; ++u) {
            int d = dv[u];
            int c = d >> shift;
            int pos = atomicAdd(&loff[c], 1);
            int sd = (sv[u] << shift) | (d & mask);
            payA[pos] = make_float2(__int_as_float(sd), tv[u]);
            ef_s[pos] = fv[u];
        }
    }
    for (int i = i0 + 4 * nq + threadIdx.x; i < i1; i += blockDim.x) {
        int d = DST[i];
        int c = d >> shift;
        int pos = atomicAdd(&loff[c], 1);
        int sd = (SRC[i] << shift) | (d & mask);
        payA[pos] = make_float2(__int_as_float(sd), DIST[i]);
        ef_s[pos] = EF[i];
    }
}

// ============================ node encoder =================================

__global__ void __launch_bounds__(256) k_enc(
    const float* __restrict__ X, const float* __restrict__ W1,
    const float* __restrict__ B1, const float* __restrict__ W2,
    const float* __restrict__ B2, float* __restrict__ H0, int n)
{
    __shared__ float4 w1s[2048];
    for (int t = threadIdx.x; t < 2048; t += blockDim.x)
        w1s[t] = reinterpret_cast<const float4*>(W1)[t];
    __syncthreads();

    int i = blockIdx.x * blockDim.x + threadIdx.x;
    if (i >= n) return;

    const float4* xp = reinterpret_cast<const float4*>(X) + (size_t)i * 32;

    float acc[64];
    #pragma unroll
    for (int j = 0; j < 64; ++j) acc[j] = B1[j];

    for (int k4 = 0; k4 < 32; ++k4) {
        float4 xv = xp[k4];
        #pragma unroll
        for (int kk = 0; kk < 4; ++kk) {
            float x = (&xv.x)[kk];
            const float4* wrow = &w1s[(k4 * 4 + kk) * 16];
            #pragma unroll
            for (int j4 = 0; j4 < 16; ++j4) {
                float4 w = wrow[j4];
                acc[j4*4+0] = fmaf(x, w.x, acc[j4*4+0]);
                acc[j4*4+1] = fmaf(x, w.y, acc[j4*4+1]);
                acc[j4*4+2] = fmaf(x, w.z, acc[j4*4+2]);
                acc[j4*4+3] = fmaf(x, w.w, acc[j4*4+3]);
            }
        }
    }
    float o = B2[0];
    #pragma unroll
    for (int j = 0; j < 64; ++j)
        o = fmaf(fmaxf(acc[j], 0.f), W2[j], o);
    H0[i] = fmaxf(o, 0.f);
}

// ==================== bucketed edge passes (G-split) =======================
// partial layout: p[((c*G + g) << shift) + t]

__global__ void __launch_bounds__(256) k_passA(
    const float2* __restrict__ payA, const float* __restrict__ H0,
    const int* __restrict__ base,
    float* __restrict__ pSum, float* __restrict__ pNum, int shift, int G)
{
    __shared__ float lsum[512], lnum[512];
    int c = blockIdx.x / G, g = blockIdx.x % G;
    int bw = 1 << shift, mask = bw - 1;
    for (int t = threadIdx.x; t < bw; t += blockDim.x) { lsum[t] = 0.f; lnum[t] = 0.f; }
    __syncthreads();
    int b0 = base[c], len = base[c + 1] - b0;
    int i0 = b0 + (int)(((long long)len * g) / G);
    int i1 = b0 + (int)(((long long)len * (g + 1)) / G);
    const int T = blockDim.x;
    for (int i = i0 + (int)threadIdx.x; i < i1; i += 2 * T) {
        int jb = i + T;
        fv2 p0 = __builtin_nontemporal_load(
            reinterpret_cast<const fv2*>(payA) + i);
        fv2 p1 = {0.f, 0.f};
        bool vb = jb < i1;
        if (vb) p1 = __builtin_nontemporal_load(
                    reinterpret_cast<const fv2*>(payA) + jb);
        int sd0 = __float_as_int(p0.x);
        int sd1 = __float_as_int(p1.x);
        float h0a = H0[sd0 >> shift];
        float h0b = vb ? H0[sd1 >> shift] : 0.f;
        float e0 = __expf(p0.y);
        float e1 = __expf(p1.y);
        atomicAdd(&lsum[sd0 & mask], e0);
        atomicAdd(&lnum[sd0 & mask], e0 * h0a);
        if (vb) {
            atomicAdd(&lsum[sd1 & mask], e1);
            atomicAdd(&lnum[sd1 & mask], e1 * h0b);
        }
    }
    __syncthreads();
    size_t po = (size_t)blockIdx.x << shift;
    for (int t = threadIdx.x; t < bw; t += blockDim.x) {
        pSum[po + t] = lsum[t];
        pNum[po + t] = lnum[t];
    }
}

__global__ void __launch_bounds__(256) k_finA(
    const float* __restrict__ pSum, const float* __restrict__ pNum,
    float* __restrict__ H1, int shift, int n, int G)
{
    int d = blockIdx.x * blockDim.x + threadIdx.x;
    if (d >= n) return;
    int c = d >> shift, t = d & ((1 << shift) - 1);
    size_t b = (size_t)c * G << shift;
    int bw = 1 << shift;
    float s = 0.f, m = 0.f;
    for (int g = 0; g < G; ++g) {
        s += pSum[b + (size_t)g * bw + t];
        m += pNum[b + (size_t)g * bw + t];
    }
    H1[d] = (s != 0.f) ? m / s : 0.f;
}

// passB main: edge MLP -> e2 (overwrites ef_s) + partial agg/s2.
// No h1loc stage: hd read directly from H1 (1KB bucket window, L1-hot).
__global__ void __launch_bounds__(256) k_passB(
    const float2* __restrict__ payA, float* __restrict__ ef_s,
    const float* __restrict__ H1,
    const float* __restrict__ W1, const float* __restrict__ B1,
    const float* __restrict__ W2, const float* __restrict__ B2,
    const int* __restrict__ base,
    float* __restrict__ pAgg, float* __restrict__ pS2, int shift, int n, int G)
{
    __shared__ float lagg[512], ls2[512];
    const fv2 ZERO2 = {0.f, 0.f};
    int bw = 1 << shift, mask = bw - 1;
    int c = blockIdx.x / G, g = blockIdx.x % G;
    int d0 = c << shift;
    for (int t = threadIdx.x; t < bw; t += blockDim.x) {
        lagg[t] = 0.f;
        ls2[t] = 0.f;
    }
    __syncthreads();
    const float b2 = B2[0];
    int b0 = base[c], len = base[c + 1] - b0;
    int i0 = b0 + (int)(((long long)len * g) / G);
    int i1 = b0 + (int)(((long long)len * (g + 1)) / G);
    const int T = blockDim.x;

    int i = i0 + (int)threadIdx.x;
    fv2 pa[4]; float xf[4];
    #pragma unroll
    for (int u = 0; u < 4; ++u) {
        int j = i + u * T;
        pa[u] = ZERO2; xf[u] = 0.f;
        if (j < i1) {
            pa[u] = __builtin_nontemporal_load(
                reinterpret_cast<const fv2*>(payA) + j);
            xf[u] = __builtin_nontemporal_load(ef_s + j);
        }
    }
    while (i < i1) {
        int inext = i + 4 * T;
        // prefetch next chunk BEFORE the store/atomic phase of this chunk
        fv2 pb[4]; float xg[4];
        #pragma unroll
        for (int u = 0; u < 4; ++u) {
            int j = inext + u * T;
            pb[u] = ZERO2; xg[u] = 0.f;
            if (j < i1) {
                pb[u] = __builtin_nontemporal_load(
                    reinterpret_cast<const fv2*>(payA) + j);
                xg[u] = __builtin_nontemporal_load(ef_s + j);
            }
        }
        // gathers + packed MLP
        fv2 x0v[4], hsv[4], hdv[4], o2[4];
        int lo[4];
        #pragma unroll
        for (int u = 0; u < 4; ++u) {
            int sd = __float_as_int(pa[u].x);
            lo[u] = sd & mask;
            float hs = H1[sd >> shift];
            float hd = H1[d0 + lo[u]];      // L1-resident 1KB window
            fv2 xt; xt.x = xf[u]; xt.y = xf[u];
            x0v[u] = xt;
            fv2 ht; ht.x = hs; ht.y = hs;
            hsv[u] = ht;
            fv2 dt; dt.x = hd; dt.y = hd;
            hdv[u] = dt;
            o2[u] = ZERO2;
        }
        #pragma unroll 4
        for (int j = 0; j < 64; j += 2) {
            fv2 aj = *reinterpret_cast<const fv2*>(W1 + j);
            fv2 bj = *reinterpret_cast<const fv2*>(W1 + 64 + j);
            fv2 cj = *reinterpret_cast<const fv2*>(W1 + 128 + j);
            fv2 dj = *reinterpret_cast<const fv2*>(B1 + j);
            fv2 vj = *reinterpret_cast<const fv2*>(W2 + j);
            #pragma unroll
            for (int u = 0; u < 4; ++u) {
                fv2 t = FMA2(x0v[u], aj,
                         FMA2(hsv[u], bj, FMA2(hdv[u], cj, dj)));
                t = MAX2(t, ZERO2);
                o2[u] = FMA2(t, vj, o2[u]);
            }
        }
        #pragma unroll
        for (int u = 0; u < 4; ++u) {
            int j = i + u * T;
            if (j < i1) {
                float eh = fmaxf(o2[u].x + o2[u].y + b2, 0.f);
                float ex = __expf(eh);
                ef_s[j] = ex;
                atomicAdd(&lagg[lo[u]], eh);
                atomicAdd(&ls2[lo[u]], ex);
            }
        }
        i = inext;
        #pragma unroll
        for (int u = 0; u < 4; ++u) { pa[u] = pb[u]; xf[u] = xg[u]; }
    }
    __syncthreads();
    size_t po = (size_t)blockIdx.x << shift;
    for (int t = threadIdx.x; t < bw; t += blockDim.x) {
        pAgg[po + t] = lagg[t];
        pS2[po + t] = ls2[t];
    }
}

// finB: sum partials; H2 = nuMLP(agg, h1); S2
__global__ void __launch_bounds__(256) k_finB(
    const float* __restrict__ pAgg, const float* __restrict__ pS2,
    const float* __restrict__ H1,
    const float* __restrict__ NW1, const float* __restrict__ NB1,
    const float* __restrict__ NW2, const float* __restrict__ NB2,
    float* __restrict__ H2, float* __restrict__ S2, int shift, int n, int G)
{
    int d = blockIdx.x * blockDim.x + threadIdx.x;
    if (d >= n) return;
    int c = d >> shift, t = d & ((1 << shift) - 1);
    size_t b = (size_t)c * G << shift;
    int bw = 1 << shift;
    float agg = 0.f, s2 = 0.f;
    for (int g = 0; g < G; ++g) {
        agg += pAgg[b + (size_t)g * bw + t];
        s2  += pS2[b + (size_t)g * bw + t];
    }
    float xh = H1[d];
    float o = NB2[0];
    #pragma unroll 4
    for (int j = 0; j < 64; ++j) {
        float a = fmaf(agg, NW1[j], fmaf(xh, NW1[64 + j], NB1[j]));
        o = fmaf(fmaxf(a, 0.f), NW2[j], o);
    }
    H2[d] = fmaxf(o, 0.f);
    S2[d] = s2;
}

// passC main: partial num2 (2-edge ILP)
__global__ void __launch_bounds__(256) k_passC(
    const float2* __restrict__ payA, const float* __restrict__ e2_s,
    const float* __restrict__ H2, const int* __restrict__ base,
    float* __restrict__ pNum, int shift, int G)
{
    __shared__ float lnum[512];
    int c = blockIdx.x / G, g = blockIdx.x % G;
    int bw = 1 << shift, mask = bw - 1;
    for (int t = threadIdx.x; t < bw; t += blockDim.x) lnum[t] = 0.f;
    __syncthreads();
    int b0 = base[c], len = base[c + 1] - b0;
    int i0 = b0 + (int)(((long long)len * g) / G);
    int i1 = b0 + (int)(((long long)len * (g + 1)) / G);
    const int T = blockDim.x;
    for (int i = i0 + (int)threadIdx.x; i < i1; i += 2 * T) {
        int jb = i + T;
        bool vb = jb < i1;
        fv2 p0 = __builtin_nontemporal_load(
            reinterpret_cast<const fv2*>(payA) + i);
        float e0 = __builtin_nontemporal_load(e2_s + i);
        fv2 p1 = {0.f, 0.f};
        float e1 = 0.f;
        if (vb) {
            p1 = __builtin_nontemporal_load(
                reinterpret_cast<const fv2*>(payA) + jb);
            e1 = __builtin_nontemporal_load(e2_s + jb);
        }
        int sd0 = __float_as_int(p0.x);
        int sd1 = __float_as_int(p1.x);
        float m0 = e0 * H2[sd0 >> shift];
        float m1 = vb ? e1 * H2[sd1 >> shift] : 0.f;
        atomicAdd(&lnum[sd0 & mask], m0);
        if (vb) atomicAdd(&lnum[sd1 & mask], m1);
    }
    __syncthreads();
    size_t po = (size_t)blockIdx.x << shift;
    for (int t = threadIdx.x; t < bw; t += blockDim.x)
        pNum[po + t] = lnum[t];
}

// finC: sum partials; OUT = decMLP(num2/s2)
__global__ void __launch_bounds__(256) k_finC(
    const float* __restrict__ pNum, const float* __restrict__ S2,
    const float* __restrict__ W1, const float* __restrict__ B1,
    const float* __restrict__ W2, const float* __restrict__ B2,
    float* __restrict__ OUT, int shift, int n, int G)
{
    int d = blockIdx.x * blockDim.x + threadIdx.x;
    if (d >= n) return;
    int c = d >> shift, t = d & ((1 << shift) - 1);
    size_t b = (size_t)c * G << shift;
    int bw = 1 << shift;
    float m = 0.f;
    for (int g = 0; g < G; ++g) m += pNum[b + (size_t)g * bw + t];
    float s = S2[d];
    float x = (s != 0.f) ? m / s : 0.f;
    float o = B2[0];
    #pragma unroll 4
    for (int j = 0; j < 64; ++j) {
        float a = fmaf(x, W1[j], B1[j]);
        o = fmaf(fmaxf(a, 0.f), W2[j], o);
    }
    OUT[d] = fmaxf(o, 0.f);
}

// ===================== fallback (atomic path) ==============================

__device__ __forceinline__ void atomAddF(float* p, float v) { unsafeAtomicAdd(p, v); }

__global__ void k_zero(float* __restrict__ p, int n) {
    int i = blockIdx.x * blockDim.x + threadIdx.x;
    if (i < n) p[i] = 0.f;
}

__global__ void __launch_bounds__(256) k_agg1(
    const float* __restrict__ DIST, const int* __restrict__ SRC,
    const int* __restrict__ DST, const float* __restrict__ H0,
    float* __restrict__ S1, float* __restrict__ NUM1, int e)
{
    int i = blockIdx.x * blockDim.x + threadIdx.x;
    if (i >= e) return;
    float ev = __expf(DIST[i]);
    atomAddF(&S1[DST[i]], ev);
    atomAddF(&NUM1[DST[i]], ev * H0[SRC[i]]);
}

__global__ void k_div(const float* __restrict__ NUM, const float* __restrict__ S,
                      float* __restrict__ H, int n) {
    int i = blockIdx.x * blockDim.x + threadIdx.x;
    if (i < n) {
        float s = S[i];
        H[i] = (s != 0.f) ? NUM[i] / s : 0.f;
    }
}

__global__ void __launch_bounds__(256) k_edgeF(
    const float* __restrict__ EF, const int* __restrict__ SRC,
    const int* __restrict__ DST, const float* __restrict__ H1,
    const float* __restrict__ W1, const float* __restrict__ B1,
    const float* __restrict__ W2, const float* __restrict__ B2,
    float* __restrict__ E2, float* __restrict__ AGG, float* __restrict__ S2, int e)
{
    int i = blockIdx.x * blockDim.x + threadIdx.x;
    if (i >= e) return;
    float x0 = EF[i];
    int s = SRC[i], d = DST[i];
    float h_s = H1[s], h_d = H1[d];
    float o = B2[0];
    for (int j = 0; j < 64; ++j) {
        float aj = fmaf(x0, W1[j], fmaf(h_s, W1[64+j], fmaf(h_d, W1[128+j], B1[j])));
        o = fmaf(fmaxf(aj, 0.f), W2[j], o);
    }
    float eh = fmaxf(o, 0.f);
    float ex = __expf(eh);
    E2[i] = ex;
    atomAddF(&AGG[d], eh);
    atomAddF(&S2[d], ex);
}

__global__ void k_nu(const float* __restrict__ AGG, const float* __restrict__ H1,
                     const float* __restrict__ W1, const float* __restrict__ B1,
                     const float* __restrict__ W2, const float* __restrict__ B2,
                     float* __restrict__ H2, int n)
{
    int i = blockIdx.x * blockDim.x + threadIdx.x;
    if (i >= n) return;
    float x0 = AGG[i], x1 = H1[i];
    float o = B2[0];
    #pragma unroll
    for (int j = 0; j < 64; ++j) {
        float a = fmaf(x0, W1[j], fmaf(x1, W1[64 + j], B1[j]));
        o = fmaf(fmaxf(a, 0.f), W2[j], o);
    }
    H2[i] = fmaxf(o, 0.f);
}

__global__ void __launch_bounds__(256) k_agg2F(
    const float* __restrict__ E2, const int* __restrict__ SRC,
    const int* __restrict__ DST, const float* __restrict__ H2,
    float* __restrict__ NUM2, int e)
{
    int i = blockIdx.x * blockDim.x + threadIdx.x;
    if (i >= e) return;
    atomAddF(&NUM2[DST[i]], E2[i] * H2[SRC[i]]);
}

__global__ void k_final(const float* __restrict__ NUM2, const float* __restrict__ S2,
                        const float* __restrict__ W1, const float* __restrict__ B1,
                        const float* __restrict__ W2, const float* __restrict__ B2,
                        float* __restrict__ OUT, int n)
{
    int i = blockIdx.x * blockDim.x + threadIdx.x;
    if (i >= n) return;
    float s = S2[i];
    float x = (s != 0.f) ? NUM2[i] / s : 0.f;
    float o = B2[0];
    #pragma unroll
    for (int j = 0; j < 64; ++j) {
        float a = fmaf(x, W1[j], B1[j]);
        o = fmaf(fmaxf(a, 0.f), W2[j], o);
    }
    OUT[i] = fmaxf(o, 0.f);
}

// ============================ launch =======================================

extern "C" void kernel_launch(void* const* d_in, const int* in_sizes, int n_in,
                              void* d_out, int out_size, void* d_ws, size_t ws_size,
                              hipStream_t stream)
{
    const float* node_feat = (const float*)d_in[0];
    const float* edge_feat = (const float*)d_in[1];
    const float* edge_dist = (const float*)d_in[2];
    const int*   src       = (const int*)d_in[3];
    const int*   dst       = (const int*)d_in[4];
    const float* enc_w1 = (const float*)d_in[5];
    const float* enc_b1 = (const float*)d_in[6];
    const float* enc_w2 = (const float*)d_in[7];
    const float* enc_b2 = (const float*)d_in[8];
    const float* nu_w1  = (const float*)d_in[9];
    const float* nu_b1  = (const float*)d_in[10];
    const float* nu_w2  = (const float*)d_in[11];
    const float* nu_b2  = (const float*)d_in[12];
    const float* eu_w1  = (const float*)d_in[13];
    const float* eu_b1  = (const float*)d_in[14];
    const float* eu_w2  = (const float*)d_in[15];
    const float* eu_b2  = (const float*)d_in[16];
    const float* dec_w1 = (const float*)d_in[17];
    const float* dec_b1 = (const float*)d_in[18];
    const float* dec_w2 = (const float*)d_in[19];
    const float* dec_b2 = (const float*)d_in[20];

    const int n = in_sizes[0] / 128;
    const int e = in_sizes[1];
    const int B = 256;

    // bucket width 256 (shift=8): ~391 buckets for n=100k; bins/writeback
    // halve vs shift=9. Cap buckets at 512 for LDS tables.
    int shift = 8;
    while ((((n + (1 << shift) - 1) >> shift) > 512) && shift < 12) shift++;
    const int nbkt = (n + (1 << shift) - 1) >> shift;
    int epb = (e + NHB - 1) / NHB;
    epb = (epb + 3) & ~3;

    // ws layout (4B words): h0,h1,h2,s2 [4n] | base[nbkt+1] bktCnt[nbkt]
    // hist[nbkt*NHB] | pad8 | payA[2e] | ef_s[e] | pP0 | pP1
    float* ws = (float*)d_ws;
    size_t w = (size_t)4 * n;
    int* base   = (int*)(ws + w); w += nbkt + 1;
    int* bktCnt = (int*)(ws + w); w += nbkt;
    int* hist   = (int*)(ws + w); w += (size_t)nbkt * NHB;
    w = (w + 1) & ~(size_t)1;
    float2* payA = (float2*)(ws + w); w += (size_t)2 * e;
    float* ef_s  = ws + w; w += e;

    // pick largest G in {8,4,2,1} whose partial arrays fit the workspace
    int G = 8;
    size_t psz;
    size_t need;
    for (;;) {
        psz = ((size_t)nbkt * G) << shift;
        need = (w + 2 * psz) * 4;
        if (need <= ws_size || G == 1) break;
        G >>= 1;
    }
    float* pP0 = ws + w;
    float* pP1 = ws + w + psz;

    float* h0 = ws;
    float* h1 = ws + (size_t)1 * n;
    float* h2 = ws + (size_t)2 * n;
    float* s2 = ws + (size_t)3 * n;

    if (ws_size >= need && nbkt <= 512 && (1 << shift) <= 512 &&
        ((size_t)n << shift) < (1u << 30)) {
        const int gE = nbkt * G;
        hipLaunchKernelGGL(k_chist, dim3(NHB), dim3(1024), 0, stream,
                           dst, hist, e, nbkt, shift, epb);
        hipLaunchKernelGGL(k_scanA, dim3(nbkt), dim3(B), 0, stream, hist, bktCnt);
        hipLaunchKernelGGL(k_scanB, dim3(1), dim3(B), 0, stream, bktCnt, base, nbkt, e);
        hipLaunchKernelGGL(k_scatter, dim3(NHB), dim3(1024), 0, stream,
                           dst, src, edge_dist, edge_feat, hist, base,
                           payA, ef_s, e, nbkt, shift, epb);
        hipLaunchKernelGGL(k_enc, dim3((n + B - 1) / B), dim3(B), 0, stream,
                           node_feat, enc_w1, enc_b1, enc_w2, enc_b2, h0, n);
        hipLaunchKernelGGL(k_passA, dim3(gE), dim3(B), 0, stream,
                           payA, h0, base, pP0, pP1, shift, G);
        hipLaunchKernelGGL(k_finA, dim3((n + B - 1) / B), dim3(B), 0, stream,
                           pP0, pP1, h1, shift, n, G);
        hipLaunchKernelGGL(k_passB, dim3(gE), dim3(B), 0, stream,
                           payA, ef_s, h1, eu_w1, eu_b1, eu_w2, eu_b2, base,
                           pP0, pP1, shift, n, G);
        hipLaunchKernelGGL(k_finB, dim3((n + B - 1) / B), dim3(B), 0, stream,
                           pP0, pP1, h1, nu_w1, nu_b1, nu_w2, nu_b2, h2, s2,
                           shift, n, G);
        hipLaunchKernelGGL(k_passC, dim3(gE), dim3(B), 0, stream,
                           payA, ef_s /*e2*/, h2, base, pP0, shift, G);
        hipLaunchKernelGGL(k_finC, dim3((n + B - 1) / B), dim3(B), 0, stream,
                           pP0, s2, dec_w1, dec_b1, dec_w2, dec_b2,
                           (float*)d_out, shift, n, G);
    } else {
        // fallback: atomic path (needs 8n + e floats)
        float* agg  = ws + (size_t)2 * n;
        float* s1   = ws + (size_t)4 * n;
        float* num1 = ws + (size_t)5 * n;
        float* num2 = ws + (size_t)6 * n;
        float* h2f  = ws + (size_t)7 * n;
        float* e2   = ws + (size_t)8 * n;
        hipLaunchKernelGGL(k_zero, dim3((5 * n + B - 1) / B), dim3(B), 0, stream,
                           agg, 5 * n);
        hipLaunchKernelGGL(k_enc, dim3((n + B - 1) / B), dim3(B), 0, stream,
                           node_feat, enc_w1, enc_b1, enc_w2, enc_b2, h0, n);
        hipLaunchKernelGGL(k_agg1, dim3((e + B - 1) / B), dim3(B), 0, stream,
                           edge_dist, src, dst, h0, s1, num1, e);
        hipLaunchKernelGGL(k_div, dim3((n + B - 1) / B), dim3(B), 0, stream,
                           num1, s1, h1, n);
        hipLaunchKernelGGL(k_edgeF, dim3((e + B - 1) / B), dim3(B), 0, stream,
                           edge_feat, src, dst, h1, eu_w1, eu_b1, eu_w2, eu_b2,
                           e2, agg, s2, e);
        hipLaunchKernelGGL(k_nu, dim3((n + B - 1) / B), dim3(B), 0, stream,
                           agg, h1, nu_w1, nu_b1, nu_w2, nu_b2, h2f, n);
        hipLaunchKernelGGL(k_agg2F, dim3((e + B - 1) / B), dim3(B), 0, stream,
                           e2, src, dst, h2f, num2, e);
        hipLaunchKernelGGL(k_final, dim3((n + B - 1) / B), dim3(B), 0, stream,
                           num2, s2, dec_w1, dec_b1, dec_w2, dec_b2, (float*)d_out, n);
    }
}

// Round 15
// 392.335 us; speedup vs baseline: 1.0080x; 1.0071x over previous
//
#include <hip/hip_runtime.h>

// ---------------------------------------------------------------------------
// GraphElementNetwork forward, bucketed path v14:
//  - shift=9 restored (r14: shift=8 re-triggered scatter write-amp, 335MB).
//  - passB: 2-deep software pipeline with GATHER prefetch — payload loaded
//    2 chunks ahead, H1[src]/H1[dst] gathers issued 1 chunk ahead (from the
//    ready pb), so gather latency hides under the current chunk's MLP.
//    (r10-r13: only payload was prefetched; gathers stalled every chunk.)
//  - no h1loc stage (hd from H1 direct; 2KB window L1-hot).
//  - passA/passC: 4-edge gather-batched ILP.
//  - chist/scatter 1024-thr (r9); weights wave-uniform scalar loads (r6);
//    packed fv2 MLP (r8); G auto {16,8,4,2,1}.
// ---------------------------------------------------------------------------

#define NHB 256   // histogram / scatter blocks

typedef int   iv4 __attribute__((ext_vector_type(4)));
typedef float fv4 __attribute__((ext_vector_type(4)));
typedef float fv2 __attribute__((ext_vector_type(2)));

#if __has_builtin(__builtin_elementwise_fma)
#define FMA2(a, b, c) __builtin_elementwise_fma((a), (b), (c))
#else
static __device__ __forceinline__ fv2 FMA2(fv2 a, fv2 b, fv2 c) {
    fv2 r; r.x = fmaf(a.x, b.x, c.x); r.y = fmaf(a.y, b.y, c.y); return r;
}
#endif
#if __has_builtin(__builtin_elementwise_max)
#define MAX2(a, b) __builtin_elementwise_max((a), (b))
#else
static __device__ __forceinline__ fv2 MAX2(fv2 a, fv2 b) {
    fv2 r; r.x = fmaxf(a.x, b.x); r.y = fmaxf(a.y, b.y); return r;
}
#endif

// ============================ bucketing ====================================

__global__ void __launch_bounds__(1024) k_chist(
    const int* __restrict__ DST, int* __restrict__ hist,
    int e, int nbkt, int shift, int epb)
{
    __shared__ int lh[512];
    for (int c = threadIdx.x; c < nbkt; c += blockDim.x) lh[c] = 0;
    __syncthreads();
    int b = blockIdx.x;
    int i0 = b * epb, i1 = min(i0 + epb, e);
    int nq = (i1 > i0) ? ((i1 - i0) >> 2) : 0;
    const iv4* D4 = reinterpret_cast<const iv4*>(DST + i0);
    for (int q = threadIdx.x; q < nq; q += blockDim.x) {
        iv4 d = D4[q];
        atomicAdd(&lh[d.x >> shift], 1);
        atomicAdd(&lh[d.y >> shift], 1);
        atomicAdd(&lh[d.z >> shift], 1);
        atomicAdd(&lh[d.w >> shift], 1);
    }
    for (int i = i0 + 4 * nq + threadIdx.x; i < i1; i += blockDim.x)
        atomicAdd(&lh[DST[i] >> shift], 1);
    __syncthreads();
    for (int c = threadIdx.x; c < nbkt; c += blockDim.x)
        hist[(size_t)c * NHB + b] = lh[c];
}

__global__ void __launch_bounds__(256) k_scanA(
    int* __restrict__ hist, int* __restrict__ bktCnt)
{
    int c = blockIdx.x;
    int* row = hist + (size_t)c * NHB;
    __shared__ int part[256];
    int t = threadIdx.x;
    int v = row[t];
    part[t] = v;
    __syncthreads();
    for (int off = 1; off < 256; off <<= 1) {
        int x = 0;
        if (t >= off) x = part[t - off];
        __syncthreads();
        part[t] += x;
        __syncthreads();
    }
    if (t == 255) bktCnt[c] = part[255];
    row[t] = part[t] - v;
}

__global__ void __launch_bounds__(256) k_scanB(
    const int* __restrict__ bktCnt, int* __restrict__ base, int nbkt, int e)
{
    __shared__ int part[256];
    int t = threadIdx.x;
    int v[4];
    int sum = 0;
    #pragma unroll
    for (int u = 0; u < 4; ++u) {
        int idx = t * 4 + u;
        v[u] = (idx < nbkt) ? bktCnt[idx] : 0;
        sum += v[u];
    }
    part[t] = sum;
    __syncthreads();
    for (int off = 1; off < 256; off <<= 1) {
        int x = 0;
        if (t >= off) x = part[t - off];
        __syncthreads();
        part[t] += x;
        __syncthreads();
    }
    int run = (t == 0) ? 0 : part[t - 1];
    #pragma unroll
    for (int u = 0; u < 4; ++u) {
        int idx = t * 4 + u;
        if (idx < nbkt) base[idx] = run;
        run += v[u];
    }
    if (t == 0) base[nbkt] = e;
}

__global__ void __launch_bounds__(1024) k_scatter(
    const int* __restrict__ DST, const int* __restrict__ SRC,
    const float* __restrict__ DIST, const float* __restrict__ EF,
    const int* __restrict__ hist, const int* __restrict__ base,
    float2* __restrict__ payA, float* __restrict__ ef_s,
    int e, int nbkt, int shift, int epb)
{
    __shared__ int loff[512];
    int b = blockIdx.x;
    for (int c = threadIdx.x; c < nbkt; c += blockDim.x)
        loff[c] = base[c] + hist[(size_t)c * NHB + b];
    __syncthreads();
    int i0 = b * epb, i1 = min(i0 + epb, e);
    if (i0 >= i1) return;
    int mask = (1 << shift) - 1;
    int nq = (i1 - i0) >> 2;
    const iv4* D4 = reinterpret_cast<const iv4*>(DST + i0);
    const iv4* S4 = reinterpret_cast<const iv4*>(SRC + i0);
    const fv4* T4 = reinterpret_cast<const fv4*>(DIST + i0);
    const fv4* F4 = reinterpret_cast<const fv4*>(EF + i0);
    for (int q = threadIdx.x; q < nq; q += blockDim.x) {
        iv4 dv = __builtin_nontemporal_load(D4 + q);
        iv4 sv = __builtin_nontemporal_load(S4 + q);
        fv4 tv = __builtin_nontemporal_load(T4 + q);
        fv4 fv = __builtin_nontemporal_load(F4 + q);
        #pragma unroll
        for (int u = 0; u < 4; ++u) {
            int d = dv[u];
            int c = d >> shift;
            int pos = atomicAdd(&loff[c], 1);
            int sd = (sv[u] << shift) | (d & mask);
            payA[pos] = make_float2(__int_as_float(sd), tv[u]);
            ef_s[pos] = fv[u];
        }
    }
    for (int i = i0 + 4 * nq + threadIdx.x; i < i1; i += blockDim.x) {
        int d = DST[i];
        int c = d >> shift;
        int pos = atomicAdd(&loff[c], 1);
        int sd = (SRC[i] << shift) | (d & mask);
        payA[pos] = make_float2(__int_as_float(sd), DIST[i]);
        ef_s[pos] = EF[i];
    }
}

// ============================ node encoder =================================

__global__ void __launch_bounds__(256) k_enc(
    const float* __restrict__ X, const float* __restrict__ W1,
    const float* __restrict__ B1, const float* __restrict__ W2,
    const float* __restrict__ B2, float* __restrict__ H0, int n)
{
    __shared__ float4 w1s[2048];
    for (int t = threadIdx.x; t < 2048; t += blockDim.x)
        w1s[t] = reinterpret_cast<const float4*>(W1)[t];
    __syncthreads();

    int i = blockIdx.x * blockDim.x + threadIdx.x;
    if (i >= n) return;

    const float4* xp = reinterpret_cast<const float4*>(X) + (size_t)i * 32;

    float acc[64];
    #pragma unroll
    for (int j = 0; j < 64; ++j) acc[j] = B1[j];

    for (int k4 = 0; k4 < 32; ++k4) {
        float4 xv = xp[k4];
        #pragma unroll
        for (int kk = 0; kk < 4; ++kk) {
            float x = (&xv.x)[kk];
            const float4* wrow = &w1s[(k4 * 4 + kk) * 16];
            #pragma unroll
            for (int j4 = 0; j4 < 16; ++j4) {
                float4 w = wrow[j4];
                acc[j4*4+0] = fmaf(x, w.x, acc[j4*4+0]);
                acc[j4*4+1] = fmaf(x, w.y, acc[j4*4+1]);
                acc[j4*4+2] = fmaf(x, w.z, acc[j4*4+2]);
                acc[j4*4+3] = fmaf(x, w.w, acc[j4*4+3]);
            }
        }
    }
    float o = B2[0];
    #pragma unroll
    for (int j = 0; j < 64; ++j)
        o = fmaf(fmaxf(acc[j], 0.f), W2[j], o);
    H0[i] = fmaxf(o, 0.f);
}

// ==================== bucketed edge passes (G-split) =======================
// partial layout: p[((c*G + g) << shift) + t]

__global__ void __launch_bounds__(256) k_passA(
    const float2* __restrict__ payA, const float* __restrict__ H0,
    const int* __restrict__ base,
    float* __restrict__ pSum, float* __restrict__ pNum, int shift, int G)
{
    __shared__ float lsum[512], lnum[512];
    int c = blockIdx.x / G, g = blockIdx.x % G;
    int bw = 1 << shift, mask = bw - 1;
    for (int t = threadIdx.x; t < bw; t += blockDim.x) { lsum[t] = 0.f; lnum[t] = 0.f; }
    __syncthreads();
    int b0 = base[c], len = base[c + 1] - b0;
    int i0 = b0 + (int)(((long long)len * g) / G);
    int i1 = b0 + (int)(((long long)len * (g + 1)) / G);
    const int T = blockDim.x;
    for (int i = i0 + (int)threadIdx.x; i < i1; i += 4 * T) {
        fv2 p[4]; bool v[4]; int sd[4]; float h[4], ev[4];
        #pragma unroll
        for (int u = 0; u < 4; ++u) {
            int j = i + u * T;
            v[u] = j < i1;
            p[u] = (fv2){0.f, 0.f};
            if (v[u]) p[u] = __builtin_nontemporal_load(
                          reinterpret_cast<const fv2*>(payA) + j);
        }
        #pragma unroll
        for (int u = 0; u < 4; ++u) {
            sd[u] = __float_as_int(p[u].x);
            h[u] = v[u] ? H0[sd[u] >> shift] : 0.f;
        }
        #pragma unroll
        for (int u = 0; u < 4; ++u) ev[u] = __expf(p[u].y);
        #pragma unroll
        for (int u = 0; u < 4; ++u) {
            if (v[u]) {
                atomicAdd(&lsum[sd[u] & mask], ev[u]);
                atomicAdd(&lnum[sd[u] & mask], ev[u] * h[u]);
            }
        }
    }
    __syncthreads();
    size_t po = (size_t)blockIdx.x << shift;
    for (int t = threadIdx.x; t < bw; t += blockDim.x) {
        pSum[po + t] = lsum[t];
        pNum[po + t] = lnum[t];
    }
}

__global__ void __launch_bounds__(256) k_finA(
    const float* __restrict__ pSum, const float* __restrict__ pNum,
    float* __restrict__ H1, int shift, int n, int G)
{
    int d = blockIdx.x * blockDim.x + threadIdx.x;
    if (d >= n) return;
    int c = d >> shift, t = d & ((1 << shift) - 1);
    size_t b = (size_t)c * G << shift;
    int bw = 1 << shift;
    float s = 0.f, m = 0.f;
    for (int g = 0; g < G; ++g) {
        s += pSum[b + (size_t)g * bw + t];
        m += pNum[b + (size_t)g * bw + t];
    }
    H1[d] = (s != 0.f) ? m / s : 0.f;
}

// passB main: edge MLP -> e2 (overwrites ef_s) + partial agg/s2.
// 2-deep pipeline: payload prefetched 2 chunks ahead, H1 gathers 1 ahead.
__global__ void __launch_bounds__(256) k_passB(
    const float2* __restrict__ payA, float* __restrict__ ef_s,
    const float* __restrict__ H1,
    const float* __restrict__ W1, const float* __restrict__ B1,
    const float* __restrict__ W2, const float* __restrict__ B2,
    const int* __restrict__ base,
    float* __restrict__ pAgg, float* __restrict__ pS2, int shift, int n, int G)
{
    __shared__ float lagg[512], ls2[512];
    const fv2 ZERO2 = {0.f, 0.f};
    int bw = 1 << shift, mask = bw - 1;
    int c = blockIdx.x / G, g = blockIdx.x % G;
    int d0 = c << shift;
    for (int t = threadIdx.x; t < bw; t += blockDim.x) {
        lagg[t] = 0.f;
        ls2[t] = 0.f;
    }
    __syncthreads();
    const float b2 = B2[0];
    int b0 = base[c], len = base[c + 1] - b0;
    int i0 = b0 + (int)(((long long)len * g) / G);
    int i1 = b0 + (int)(((long long)len * (g + 1)) / G);
    const int T = blockDim.x;
    const int STEP = 4 * T;

    int i = i0 + (int)threadIdx.x;

    // prologue: pa = chunk(i), pb = chunk(i+STEP); gathers for pa
    fv2 pa[4]; float xa[4];
    fv2 pb[4]; float xb[4];
    float hsc[4], hdc[4];
    #pragma unroll
    for (int u = 0; u < 4; ++u) {
        int j = i + u * T;
        pa[u] = ZERO2; xa[u] = 0.f;
        if (j < i1) {
            pa[u] = __builtin_nontemporal_load(
                reinterpret_cast<const fv2*>(payA) + j);
            xa[u] = __builtin_nontemporal_load(ef_s + j);
        }
    }
    #pragma unroll
    for (int u = 0; u < 4; ++u) {
        int j = i + STEP + u * T;
        pb[u] = ZERO2; xb[u] = 0.f;
        if (j < i1) {
            pb[u] = __builtin_nontemporal_load(
                reinterpret_cast<const fv2*>(payA) + j);
            xb[u] = __builtin_nontemporal_load(ef_s + j);
        }
    }
    #pragma unroll
    for (int u = 0; u < 4; ++u) {
        int sd = __float_as_int(pa[u].x);
        hsc[u] = H1[sd >> shift];
        hdc[u] = H1[d0 + (sd & mask)];
    }

    while (i < i1) {
        int i2 = i + 2 * STEP;
        // depth-2 payload prefetch
        fv2 pc[4]; float xc[4];
        #pragma unroll
        for (int u = 0; u < 4; ++u) {
            int j = i2 + u * T;
            pc[u] = ZERO2; xc[u] = 0.f;
            if (j < i1) {
                pc[u] = __builtin_nontemporal_load(
                    reinterpret_cast<const fv2*>(payA) + j);
                xc[u] = __builtin_nontemporal_load(ef_s + j);
            }
        }
        // depth-1 gather prefetch (pb loaded one MLP ago -> ready)
        float hsn[4], hdn[4];
        #pragma unroll
        for (int u = 0; u < 4; ++u) {
            int sd = __float_as_int(pb[u].x);
            hsn[u] = H1[sd >> shift];
            hdn[u] = H1[d0 + (sd & mask)];
        }
        // compute phase: packed MLP on current chunk (pa, hsc, hdc)
        fv2 x0v[4], hsv[4], hdv[4], o2[4];
        int lo[4];
        #pragma unroll
        for (int u = 0; u < 4; ++u) {
            lo[u] = __float_as_int(pa[u].x) & mask;
            fv2 xt; xt.x = xa[u]; xt.y = xa[u];
            x0v[u] = xt;
            fv2 ht; ht.x = hsc[u]; ht.y = hsc[u];
            hsv[u] = ht;
            fv2 dt; dt.x = hdc[u]; dt.y = hdc[u];
            hdv[u] = dt;
            o2[u] = ZERO2;
        }
        #pragma unroll 4
        for (int j = 0; j < 64; j += 2) {
            fv2 aj = *reinterpret_cast<const fv2*>(W1 + j);
            fv2 bj = *reinterpret_cast<const fv2*>(W1 + 64 + j);
            fv2 cj = *reinterpret_cast<const fv2*>(W1 + 128 + j);
            fv2 dj = *reinterpret_cast<const fv2*>(B1 + j);
            fv2 vj = *reinterpret_cast<const fv2*>(W2 + j);
            #pragma unroll
            for (int u = 0; u < 4; ++u) {
                fv2 t = FMA2(x0v[u], aj,
                         FMA2(hsv[u], bj, FMA2(hdv[u], cj, dj)));
                t = MAX2(t, ZERO2);
                o2[u] = FMA2(t, vj, o2[u]);
            }
        }
        // store/atomic phase
        #pragma unroll
        for (int u = 0; u < 4; ++u) {
            int j = i + u * T;
            if (j < i1) {
                float eh = fmaxf(o2[u].x + o2[u].y + b2, 0.f);
                float ex = __expf(eh);
                ef_s[j] = ex;
                atomicAdd(&lagg[lo[u]], eh);
                atomicAdd(&ls2[lo[u]], ex);
            }
        }
        // rotate pipeline
        i += STEP;
        #pragma unroll
        for (int u = 0; u < 4; ++u) {
            pa[u] = pb[u]; xa[u] = xb[u];
            pb[u] = pc[u]; xb[u] = xc[u];
            hsc[u] = hsn[u]; hdc[u] = hdn[u];
        }
    }
    __syncthreads();
    size_t po = (size_t)blockIdx.x << shift;
    for (int t = threadIdx.x; t < bw; t += blockDim.x) {
        pAgg[po + t] = lagg[t];
        pS2[po + t] = ls2[t];
    }
}

// finB: sum partials; H2 = nuMLP(agg, h1); S2
__global__ void __launch_bounds__(256) k_finB(
    const float* __restrict__ pAgg, const float* __restrict__ pS2,
    const float* __restrict__ H1,
    const float* __restrict__ NW1, const float* __restrict__ NB1,
    const float* __restrict__ NW2, const float* __restrict__ NB2,
    float* __restrict__ H2, float* __restrict__ S2, int shift, int n, int G)
{
    int d = blockIdx.x * blockDim.x + threadIdx.x;
    if (d >= n) return;
    int c = d >> shift, t = d & ((1 << shift) - 1);
    size_t b = (size_t)c * G << shift;
    int bw = 1 << shift;
    float agg = 0.f, s2 = 0.f;
    for (int g = 0; g < G; ++g) {
        agg += pAgg[b + (size_t)g * bw + t];
        s2  += pS2[b + (size_t)g * bw + t];
    }
    float xh = H1[d];
    float o = NB2[0];
    #pragma unroll 4
    for (int j = 0; j < 64; ++j) {
        float a = fmaf(agg, NW1[j], fmaf(xh, NW1[64 + j], NB1[j]));
        o = fmaf(fmaxf(a, 0.f), NW2[j], o);
    }
    H2[d] = fmaxf(o, 0.f);
    S2[d] = s2;
}

// passC main: partial num2 (4-edge gather-batched ILP)
__global__ void __launch_bounds__(256) k_passC(
    const float2* __restrict__ payA, const float* __restrict__ e2_s,
    const float* __restrict__ H2, const int* __restrict__ base,
    float* __restrict__ pNum, int shift, int G)
{
    __shared__ float lnum[512];
    int c = blockIdx.x / G, g = blockIdx.x % G;
    int bw = 1 << shift, mask = bw - 1;
    for (int t = threadIdx.x; t < bw; t += blockDim.x) lnum[t] = 0.f;
    __syncthreads();
    int b0 = base[c], len = base[c + 1] - b0;
    int i0 = b0 + (int)(((long long)len * g) / G);
    int i1 = b0 + (int)(((long long)len * (g + 1)) / G);
    const int T = blockDim.x;
    for (int i = i0 + (int)threadIdx.x; i < i1; i += 4 * T) {
        fv2 p[4]; float e2[4]; bool v[4]; int sd[4]; float h[4];
        #pragma unroll
        for (int u = 0; u < 4; ++u) {
            int j = i + u * T;
            v[u] = j < i1;
            p[u] = (fv2){0.f, 0.f}; e2[u] = 0.f;
            if (v[u]) {
                p[u] = __builtin_nontemporal_load(
                    reinterpret_cast<const fv2*>(payA) + j);
                e2[u] = __builtin_nontemporal_load(e2_s + j);
            }
        }
        #pragma unroll
        for (int u = 0; u < 4; ++u) {
            sd[u] = __float_as_int(p[u].x);
            h[u] = v[u] ? H2[sd[u] >> shift] : 0.f;
        }
        #pragma unroll
        for (int u = 0; u < 4; ++u) {
            if (v[u]) atomicAdd(&lnum[sd[u] & mask], e2[u] * h[u]);
        }
    }
    __syncthreads();
    size_t po = (size_t)blockIdx.x << shift;
    for (int t = threadIdx.x; t < bw; t += blockDim.x)
        pNum[po + t] = lnum[t];
}

// finC: sum partials; OUT = decMLP(num2/s2)
__global__ void __launch_bounds__(256) k_finC(
    const float* __restrict__ pNum, const float* __restrict__ S2,
    const float* __restrict__ W1, const float* __restrict__ B1,
    const float* __restrict__ W2, const float* __restrict__ B2,
    float* __restrict__ OUT, int shift, int n, int G)
{
    int d = blockIdx.x * blockDim.x + threadIdx.x;
    if (d >= n) return;
    int c = d >> shift, t = d & ((1 << shift) - 1);
    size_t b = (size_t)c * G << shift;
    int bw = 1 << shift;
    float m = 0.f;
    for (int g = 0; g < G; ++g) m += pNum[b + (size_t)g * bw + t];
    float s = S2[d];
    float x = (s != 0.f) ? m / s : 0.f;
    float o = B2[0];
    #pragma unroll 4
    for (int j = 0; j < 64; ++j) {
        float a = fmaf(x, W1[j], B1[j]);
        o = fmaf(fmaxf(a, 0.f), W2[j], o);
    }
    OUT[d] = fmaxf(o, 0.f);
}

// ===================== fallback (atomic path) ==============================

__device__ __forceinline__ void atomAddF(float* p, float v) { unsafeAtomicAdd(p, v); }

__global__ void k_zero(float* __restrict__ p, int n) {
    int i = blockIdx.x * blockDim.x + threadIdx.x;
    if (i < n) p[i] = 0.f;
}

__global__ void __launch_bounds__(256) k_agg1(
    const float* __restrict__ DIST, const int* __restrict__ SRC,
    const int* __restrict__ DST, const float* __restrict__ H0,
    float* __restrict__ S1, float* __restrict__ NUM1, int e)
{
    int i = blockIdx.x * blockDim.x + threadIdx.x;
    if (i >= e) return;
    float ev = __expf(DIST[i]);
    atomAddF(&S1[DST[i]], ev);
    atomAddF(&NUM1[DST[i]], ev * H0[SRC[i]]);
}

__global__ void k_div(const float* __restrict__ NUM, const float* __restrict__ S,
                      float* __restrict__ H, int n) {
    int i = blockIdx.x * blockDim.x + threadIdx.x;
    if (i < n) {
        float s = S[i];
        H[i] = (s != 0.f) ? NUM[i] / s : 0.f;
    }
}

__global__ void __launch_bounds__(256) k_edgeF(
    const float* __restrict__ EF, const int* __restrict__ SRC,
    const int* __restrict__ DST, const float* __restrict__ H1,
    const float* __restrict__ W1, const float* __restrict__ B1,
    const float* __restrict__ W2, const float* __restrict__ B2,
    float* __restrict__ E2, float* __restrict__ AGG, float* __restrict__ S2, int e)
{
    int i = blockIdx.x * blockDim.x + threadIdx.x;
    if (i >= e) return;
    float x0 = EF[i];
    int s = SRC[i], d = DST[i];
    float h_s = H1[s], h_d = H1[d];
    float o = B2[0];
    for (int j = 0; j < 64; ++j) {
        float aj = fmaf(x0, W1[j], fmaf(h_s, W1[64+j], fmaf(h_d, W1[128+j], B1[j])));
        o = fmaf(fmaxf(aj, 0.f), W2[j], o);
    }
    float eh = fmaxf(o, 0.f);
    float ex = __expf(eh);
    E2[i] = ex;
    atomAddF(&AGG[d], eh);
    atomAddF(&S2[d], ex);
}

__global__ void k_nu(const float* __restrict__ AGG, const float* __restrict__ H1,
                     const float* __restrict__ W1, const float* __restrict__ B1,
                     const float* __restrict__ W2, const float* __restrict__ B2,
                     float* __restrict__ H2, int n)
{
    int i = blockIdx.x * blockDim.x + threadIdx.x;
    if (i >= n) return;
    float x0 = AGG[i], x1 = H1[i];
    float o = B2[0];
    #pragma unroll
    for (int j = 0; j < 64; ++j) {
        float a = fmaf(x0, W1[j], fmaf(x1, W1[64 + j], B1[j]));
        o = fmaf(fmaxf(a, 0.f), W2[j], o);
    }
    H2[i] = fmaxf(o, 0.f);
}

__global__ void __launch_bounds__(256) k_agg2F(
    const float* __restrict__ E2, const int* __restrict__ SRC,
    const int* __restrict__ DST, const float* __restrict__ H2,
    float* __restrict__ NUM2, int e)
{
    int i = blockIdx.x * blockDim.x + threadIdx.x;
    if (i >= e) return;
    atomAddF(&NUM2[DST[i]], E2[i] * H2[SRC[i]]);
}

__global__ void k_final(const float* __restrict__ NUM2, const float* __restrict__ S2,
                        const float* __restrict__ W1, const float* __restrict__ B1,
                        const float* __restrict__ W2, const float* __restrict__ B2,
                        float* __restrict__ OUT, int n)
{
    int i = blockIdx.x * blockDim.x + threadIdx.x;
    if (i >= n) return;
    float s = S2[i];
    float x = (s != 0.f) ? NUM2[i] / s : 0.f;
    float o = B2[0];
    #pragma unroll
    for (int j = 0; j < 64; ++j) {
        float a = fmaf(x, W1[j], B1[j]);
        o = fmaf(fmaxf(a, 0.f), W2[j], o);
    }
    OUT[i] = fmaxf(o, 0.f);
}

// ============================ launch =======================================

extern "C" void kernel_launch(void* const* d_in, const int* in_sizes, int n_in,
                              void* d_out, int out_size, void* d_ws, size_t ws_size,
                              hipStream_t stream)
{
    const float* node_feat = (const float*)d_in[0];
    const float* edge_feat = (const float*)d_in[1];
    const float* edge_dist = (const float*)d_in[2];
    const int*   src       = (const int*)d_in[3];
    const int*   dst       = (const int*)d_in[4];
    const float* enc_w1 = (const float*)d_in[5];
    const float* enc_b1 = (const float*)d_in[6];
    const float* enc_w2 = (const float*)d_in[7];
    const float* enc_b2 = (const float*)d_in[8];
    const float* nu_w1  = (const float*)d_in[9];
    const float* nu_b1  = (const float*)d_in[10];
    const float* nu_w2  = (const float*)d_in[11];
    const float* nu_b2  = (const float*)d_in[12];
    const float* eu_w1  = (const float*)d_in[13];
    const float* eu_b1  = (const float*)d_in[14];
    const float* eu_w2  = (const float*)d_in[15];
    const float* eu_b2  = (const float*)d_in[16];
    const float* dec_w1 = (const float*)d_in[17];
    const float* dec_b1 = (const float*)d_in[18];
    const float* dec_w2 = (const float*)d_in[19];
    const float* dec_b2 = (const float*)d_in[20];

    const int n = in_sizes[0] / 128;
    const int e = in_sizes[1];
    const int B = 256;

    // bucket width 512 (shift=9): scatter-side optimum (r14: shift=8 caused
    // 335MB write-amp; r7/r9: shift=9 -> 147MB).
    int shift = 9;
    while ((((n + (1 << shift) - 1) >> shift) > 512) && shift < 12) shift++;
    const int nbkt = (n + (1 << shift) - 1) >> shift;
    int epb = (e + NHB - 1) / NHB;
    epb = (epb + 3) & ~3;

    // ws layout (4B words): h0,h1,h2,s2 [4n] | base[nbkt+1] bktCnt[nbkt]
    // hist[nbkt*NHB] | pad8 | payA[2e] | ef_s[e] | pP0 | pP1
    float* ws = (float*)d_ws;
    size_t w = (size_t)4 * n;
    int* base   = (int*)(ws + w); w += nbkt + 1;
    int* bktCnt = (int*)(ws + w); w += nbkt;
    int* hist   = (int*)(ws + w); w += (size_t)nbkt * NHB;
    w = (w + 1) & ~(size_t)1;
    float2* payA = (float2*)(ws + w); w += (size_t)2 * e;
    float* ef_s  = ws + w; w += e;

    // pick largest G in {16,8,4,2,1} whose partial arrays fit the workspace
    int G = 16;
    size_t psz;
    size_t need;
    for (;;) {
        psz = ((size_t)nbkt * G) << shift;
        need = (w + 2 * psz) * 4;
        if (need <= ws_size || G == 1) break;
        G >>= 1;
    }
    float* pP0 = ws + w;
    float* pP1 = ws + w + psz;

    float* h0 = ws;
    float* h1 = ws + (size_t)1 * n;
    float* h2 = ws + (size_t)2 * n;
    float* s2 = ws + (size_t)3 * n;

    if (ws_size >= need && nbkt <= 512 && (1 << shift) <= 512 &&
        ((size_t)n << shift) < (1u << 30)) {
        const int gE = nbkt * G;
        hipLaunchKernelGGL(k_chist, dim3(NHB), dim3(1024), 0, stream,
                           dst, hist, e, nbkt, shift, epb);
        hipLaunchKernelGGL(k_scanA, dim3(nbkt), dim3(B), 0, stream, hist, bktCnt);
        hipLaunchKernelGGL(k_scanB, dim3(1), dim3(B), 0, stream, bktCnt, base, nbkt, e);
        hipLaunchKernelGGL(k_scatter, dim3(NHB), dim3(1024), 0, stream,
                           dst, src, edge_dist, edge_feat, hist, base,
                           payA, ef_s, e, nbkt, shift, epb);
        hipLaunchKernelGGL(k_enc, dim3((n + B - 1) / B), dim3(B), 0, stream,
                           node_feat, enc_w1, enc_b1, enc_w2, enc_b2, h0, n);
        hipLaunchKernelGGL(k_passA, dim3(gE), dim3(B), 0, stream,
                           payA, h0, base, pP0, pP1, shift, G);
        hipLaunchKernelGGL(k_finA, dim3((n + B - 1) / B), dim3(B), 0, stream,
                           pP0, pP1, h1, shift, n, G);
        hipLaunchKernelGGL(k_passB, dim3(gE), dim3(B), 0, stream,
                           payA, ef_s, h1, eu_w1, eu_b1, eu_w2, eu_b2, base,
                           pP0, pP1, shift, n, G);
        hipLaunchKernelGGL(k_finB, dim3((n + B - 1) / B), dim3(B), 0, stream,
                           pP0, pP1, h1, nu_w1, nu_b1, nu_w2, nu_b2, h2, s2,
                           shift, n, G);
        hipLaunchKernelGGL(k_passC, dim3(gE), dim3(B), 0, stream,
                           payA, ef_s /*e2*/, h2, base, pP0, shift, G);
        hipLaunchKernelGGL(k_finC, dim3((n + B - 1) / B), dim3(B), 0, stream,
                           pP0, s2, dec_w1, dec_b1, dec_w2, dec_b2,
                           (float*)d_out, shift, n, G);
    } else {
        // fallback: atomic path (needs 8n + e floats)
        float* agg  = ws + (size_t)2 * n;
        float* s1   = ws + (size_t)4 * n;
        float* num1 = ws + (size_t)5 * n;
        float* num2 = ws + (size_t)6 * n;
        float* h2f  = ws + (size_t)7 * n;
        float* e2   = ws + (size_t)8 * n;
        hipLaunchKernelGGL(k_zero, dim3((5 * n + B - 1) / B), dim3(B), 0, stream,
                           agg, 5 * n);
        hipLaunchKernelGGL(k_enc, dim3((n + B - 1) / B), dim3(B), 0, stream,
                           node_feat, enc_w1, enc_b1, enc_w2, enc_b2, h0, n);
        hipLaunchKernelGGL(k_agg1, dim3((e + B - 1) / B), dim3(B), 0, stream,
                           edge_dist, src, dst, h0, s1, num1, e);
        hipLaunchKernelGGL(k_div, dim3((n + B - 1) / B), dim3(B), 0, stream,
                           num1, s1, h1, n);
        hipLaunchKernelGGL(k_edgeF, dim3((e + B - 1) / B), dim3(B), 0, stream,
                           edge_feat, src, dst, h1, eu_w1, eu_b1, eu_w2, eu_b2,
                           e2, agg, s2, e);
        hipLaunchKernelGGL(k_nu, dim3((n + B - 1) / B), dim3(B), 0, stream,
                           agg, h1, nu_w1, nu_b1, nu_w2, nu_b2, h2f, n);
        hipLaunchKernelGGL(k_agg2F, dim3((e + B - 1) / B), dim3(B), 0, stream,
                           e2, src, dst, h2f, num2, e);
        hipLaunchKernelGGL(k_final, dim3((n + B - 1) / B), dim3(B), 0, stream,
                           num2, s2, dec_w1, dec_b1, dec_w2, dec_b2, (float*)d_out, n);
    }
}

// Round 16
// 377.655 us; speedup vs baseline: 1.0472x; 1.0389x over previous
//
#include <hip/hip_runtime.h>

// ---------------------------------------------------------------------------
// GraphElementNetwork forward, bucketed path v15 (= r10 best config + passC
// single-stream):
//  - r10 config: shift=9, G<=16, 1024-thr chist/scatter, 256-thr passes,
//    passB = h1loc-staged 4-edge chunk + 1-deep payload prefetch (102us).
//  - NEW: passB overwrites payA[j].y (dead dist) with e2 -> passC reads ONE
//    contiguous float2 stream (sd,e2) instead of payA+ef_s (safe: each j is
//    touched by exactly one thread; prefetch reads trail overwrites).
//  - passB floor note: 102-107us across 6 structural variants (r10-r15);
//    VALU ~26us + issue-gap floor. Don't re-litigate with micro-tweaks.
// ---------------------------------------------------------------------------

#define NHB 256   // histogram / scatter blocks

typedef int   iv4 __attribute__((ext_vector_type(4)));
typedef float fv4 __attribute__((ext_vector_type(4)));
typedef float fv2 __attribute__((ext_vector_type(2)));

#if __has_builtin(__builtin_elementwise_fma)
#define FMA2(a, b, c) __builtin_elementwise_fma((a), (b), (c))
#else
static __device__ __forceinline__ fv2 FMA2(fv2 a, fv2 b, fv2 c) {
    fv2 r; r.x = fmaf(a.x, b.x, c.x); r.y = fmaf(a.y, b.y, c.y); return r;
}
#endif
#if __has_builtin(__builtin_elementwise_max)
#define MAX2(a, b) __builtin_elementwise_max((a), (b))
#else
static __device__ __forceinline__ fv2 MAX2(fv2 a, fv2 b) {
    fv2 r; r.x = fmaxf(a.x, b.x); r.y = fmaxf(a.y, b.y); return r;
}
#endif

// ============================ bucketing ====================================

__global__ void __launch_bounds__(1024) k_chist(
    const int* __restrict__ DST, int* __restrict__ hist,
    int e, int nbkt, int shift, int epb)
{
    __shared__ int lh[512];
    for (int c = threadIdx.x; c < nbkt; c += blockDim.x) lh[c] = 0;
    __syncthreads();
    int b = blockIdx.x;
    int i0 = b * epb, i1 = min(i0 + epb, e);
    int nq = (i1 > i0) ? ((i1 - i0) >> 2) : 0;
    const iv4* D4 = reinterpret_cast<const iv4*>(DST + i0);
    for (int q = threadIdx.x; q < nq; q += blockDim.x) {
        iv4 d = D4[q];
        atomicAdd(&lh[d.x >> shift], 1);
        atomicAdd(&lh[d.y >> shift], 1);
        atomicAdd(&lh[d.z >> shift], 1);
        atomicAdd(&lh[d.w >> shift], 1);
    }
    for (int i = i0 + 4 * nq + threadIdx.x; i < i1; i += blockDim.x)
        atomicAdd(&lh[DST[i] >> shift], 1);
    __syncthreads();
    for (int c = threadIdx.x; c < nbkt; c += blockDim.x)
        hist[(size_t)c * NHB + b] = lh[c];
}

__global__ void __launch_bounds__(256) k_scanA(
    int* __restrict__ hist, int* __restrict__ bktCnt)
{
    int c = blockIdx.x;
    int* row = hist + (size_t)c * NHB;
    __shared__ int part[256];
    int t = threadIdx.x;
    int v = row[t];
    part[t] = v;
    __syncthreads();
    for (int off = 1; off < 256; off <<= 1) {
        int x = 0;
        if (t >= off) x = part[t - off];
        __syncthreads();
        part[t] += x;
        __syncthreads();
    }
    if (t == 255) bktCnt[c] = part[255];
    row[t] = part[t] - v;
}

__global__ void __launch_bounds__(256) k_scanB(
    const int* __restrict__ bktCnt, int* __restrict__ base, int nbkt, int e)
{
    __shared__ int part[256];
    int t = threadIdx.x;
    int v[4];
    int sum = 0;
    #pragma unroll
    for (int u = 0; u < 4; ++u) {
        int idx = t * 4 + u;
        v[u] = (idx < nbkt) ? bktCnt[idx] : 0;
        sum += v[u];
    }
    part[t] = sum;
    __syncthreads();
    for (int off = 1; off < 256; off <<= 1) {
        int x = 0;
        if (t >= off) x = part[t - off];
        __syncthreads();
        part[t] += x;
        __syncthreads();
    }
    int run = (t == 0) ? 0 : part[t - 1];
    #pragma unroll
    for (int u = 0; u < 4; ++u) {
        int idx = t * 4 + u;
        if (idx < nbkt) base[idx] = run;
        run += v[u];
    }
    if (t == 0) base[nbkt] = e;
}

__global__ void __launch_bounds__(1024) k_scatter(
    const int* __restrict__ DST, const int* __restrict__ SRC,
    const float* __restrict__ DIST, const float* __restrict__ EF,
    const int* __restrict__ hist, const int* __restrict__ base,
    float2* __restrict__ payA, float* __restrict__ ef_s,
    int e, int nbkt, int shift, int epb)
{
    __shared__ int loff[512];
    int b = blockIdx.x;
    for (int c = threadIdx.x; c < nbkt; c += blockDim.x)
        loff[c] = base[c] + hist[(size_t)c * NHB + b];
    __syncthreads();
    int i0 = b * epb, i1 = min(i0 + epb, e);
    if (i0 >= i1) return;
    int mask = (1 << shift) - 1;
    int nq = (i1 - i0) >> 2;
    const iv4* D4 = reinterpret_cast<const iv4*>(DST + i0);
    const iv4* S4 = reinterpret_cast<const iv4*>(SRC + i0);
    const fv4* T4 = reinterpret_cast<const fv4*>(DIST + i0);
    const fv4* F4 = reinterpret_cast<const fv4*>(EF + i0);
    for (int q = threadIdx.x; q < nq; q += blockDim.x) {
        iv4 dv = __builtin_nontemporal_load(D4 + q);
        iv4 sv = __builtin_nontemporal_load(S4 + q);
        fv4 tv = __builtin_nontemporal_load(T4 + q);
        fv4 fv = __builtin_nontemporal_load(F4 + q);
        #pragma unroll
        for (int u = 0; u < 4; ++u) {
            int d = dv[u];
            int c = d >> shift;
            int pos = atomicAdd(&loff[c], 1);
            int sd = (sv[u] << shift) | (d & mask);
            payA[pos] = make_float2(__int_as_float(sd), tv[u]);
            ef_s[pos] = fv[u];
        }
    }
    for (int i = i0 + 4 * nq + threadIdx.x; i < i1; i += blockDim.x) {
        int d = DST[i];
        int c = d >> shift;
        int pos = atomicAdd(&loff[c], 1);
        int sd = (SRC[i] << shift) | (d & mask);
        payA[pos] = make_float2(__int_as_float(sd), DIST[i]);
        ef_s[pos] = EF[i];
    }
}

// ============================ node encoder =================================

__global__ void __launch_bounds__(256) k_enc(
    const float* __restrict__ X, const float* __restrict__ W1,
    const float* __restrict__ B1, const float* __restrict__ W2,
    const float* __restrict__ B2, float* __restrict__ H0, int n)
{
    __shared__ float4 w1s[2048];
    for (int t = threadIdx.x; t < 2048; t += blockDim.x)
        w1s[t] = reinterpret_cast<const float4*>(W1)[t];
    __syncthreads();

    int i = blockIdx.x * blockDim.x + threadIdx.x;
    if (i >= n) return;

    const float4* xp = reinterpret_cast<const float4*>(X) + (size_t)i * 32;

    float acc[64];
    #pragma unroll
    for (int j = 0; j < 64; ++j) acc[j] = B1[j];

    for (int k4 = 0; k4 < 32; ++k4) {
        float4 xv = xp[k4];
        #pragma unroll
        for (int kk = 0; kk < 4; ++kk) {
            float x = (&xv.x)[kk];
            const float4* wrow = &w1s[(k4 * 4 + kk) * 16];
            #pragma unroll
            for (int j4 = 0; j4 < 16; ++j4) {
                float4 w = wrow[j4];
                acc[j4*4+0] = fmaf(x, w.x, acc[j4*4+0]);
                acc[j4*4+1] = fmaf(x, w.y, acc[j4*4+1]);
                acc[j4*4+2] = fmaf(x, w.z, acc[j4*4+2]);
                acc[j4*4+3] = fmaf(x, w.w, acc[j4*4+3]);
            }
        }
    }
    float o = B2[0];
    #pragma unroll
    for (int j = 0; j < 64; ++j)
        o = fmaf(fmaxf(acc[j], 0.f), W2[j], o);
    H0[i] = fmaxf(o, 0.f);
}

// ==================== bucketed edge passes (G-split) =======================
// partial layout: p[((c*G + g) << shift) + t]

__global__ void __launch_bounds__(256) k_passA(
    const float2* __restrict__ payA, const float* __restrict__ H0,
    const int* __restrict__ base,
    float* __restrict__ pSum, float* __restrict__ pNum, int shift, int G)
{
    __shared__ float lsum[512], lnum[512];
    int c = blockIdx.x / G, g = blockIdx.x % G;
    int bw = 1 << shift, mask = bw - 1;
    for (int t = threadIdx.x; t < bw; t += blockDim.x) { lsum[t] = 0.f; lnum[t] = 0.f; }
    __syncthreads();
    int b0 = base[c], len = base[c + 1] - b0;
    int i0 = b0 + (int)(((long long)len * g) / G);
    int i1 = b0 + (int)(((long long)len * (g + 1)) / G);
    const int T = blockDim.x;
    for (int i = i0 + (int)threadIdx.x; i < i1; i += 4 * T) {
        fv2 p[4]; bool v[4]; int sd[4]; float h[4], ev[4];
        #pragma unroll
        for (int u = 0; u < 4; ++u) {
            int j = i + u * T;
            v[u] = j < i1;
            p[u].x = 0.f; p[u].y = 0.f;
            if (v[u]) p[u] = __builtin_nontemporal_load(
                          reinterpret_cast<const fv2*>(payA) + j);
        }
        #pragma unroll
        for (int u = 0; u < 4; ++u) {
            sd[u] = __float_as_int(p[u].x);
            h[u] = v[u] ? H0[sd[u] >> shift] : 0.f;
        }
        #pragma unroll
        for (int u = 0; u < 4; ++u) ev[u] = __expf(p[u].y);
        #pragma unroll
        for (int u = 0; u < 4; ++u) {
            if (v[u]) {
                atomicAdd(&lsum[sd[u] & mask], ev[u]);
                atomicAdd(&lnum[sd[u] & mask], ev[u] * h[u]);
            }
        }
    }
    __syncthreads();
    size_t po = (size_t)blockIdx.x << shift;
    for (int t = threadIdx.x; t < bw; t += blockDim.x) {
        pSum[po + t] = lsum[t];
        pNum[po + t] = lnum[t];
    }
}

__global__ void __launch_bounds__(256) k_finA(
    const float* __restrict__ pSum, const float* __restrict__ pNum,
    float* __restrict__ H1, int shift, int n, int G)
{
    int d = blockIdx.x * blockDim.x + threadIdx.x;
    if (d >= n) return;
    int c = d >> shift, t = d & ((1 << shift) - 1);
    size_t b = (size_t)c * G << shift;
    int bw = 1 << shift;
    float s = 0.f, m = 0.f;
    for (int g = 0; g < G; ++g) {
        s += pSum[b + (size_t)g * bw + t];
        m += pNum[b + (size_t)g * bw + t];
    }
    H1[d] = (s != 0.f) ? m / s : 0.f;
}

// passB main (r10 structure): edge MLP; writes e2 into payA[j].y (in-place,
// dist is dead after passA); partial agg/s2 into LDS bins.
__global__ void __launch_bounds__(256) k_passB(
    float2* __restrict__ payA, const float* __restrict__ ef_s,
    const float* __restrict__ H1,
    const float* __restrict__ W1, const float* __restrict__ B1,
    const float* __restrict__ W2, const float* __restrict__ B2,
    const int* __restrict__ base,
    float* __restrict__ pAgg, float* __restrict__ pS2, int shift, int n, int G)
{
    __shared__ float h1loc[512], lagg[512], ls2[512];
    const fv2 ZERO2 = {0.f, 0.f};
    int bw = 1 << shift, mask = bw - 1;
    int c = blockIdx.x / G, g = blockIdx.x % G;
    int d0 = c << shift;
    for (int t = threadIdx.x; t < bw; t += blockDim.x) {
        int d = d0 + t;
        h1loc[t] = (d < n) ? H1[d] : 0.f;
        lagg[t] = 0.f;
        ls2[t] = 0.f;
    }
    __syncthreads();
    const float b2 = B2[0];
    int b0 = base[c], len = base[c + 1] - b0;
    int i0 = b0 + (int)(((long long)len * g) / G);
    int i1 = b0 + (int)(((long long)len * (g + 1)) / G);
    const int T = blockDim.x;

    int i = i0 + (int)threadIdx.x;
    fv2 pa[4]; float xf[4];
    #pragma unroll
    for (int u = 0; u < 4; ++u) {
        int j = i + u * T;
        pa[u] = ZERO2; xf[u] = 0.f;
        if (j < i1) {
            pa[u] = __builtin_nontemporal_load(
                reinterpret_cast<const fv2*>(payA) + j);
            xf[u] = __builtin_nontemporal_load(ef_s + j);
        }
    }
    float* payF = reinterpret_cast<float*>(payA);
    while (i < i1) {
        int inext = i + 4 * T;
        // prefetch next chunk BEFORE the store/atomic phase of this chunk
        fv2 pb[4]; float xg[4];
        #pragma unroll
        for (int u = 0; u < 4; ++u) {
            int j = inext + u * T;
            pb[u] = ZERO2; xg[u] = 0.f;
            if (j < i1) {
                pb[u] = __builtin_nontemporal_load(
                    reinterpret_cast<const fv2*>(payA) + j);
                xg[u] = __builtin_nontemporal_load(ef_s + j);
            }
        }
        // gathers + packed MLP
        fv2 x0v[4], hsv[4], hdv[4], o2[4];
        int lo[4];
        #pragma unroll
        for (int u = 0; u < 4; ++u) {
            int sd = __float_as_int(pa[u].x);
            lo[u] = sd & mask;
            float hs = H1[sd >> shift];
            float hd = h1loc[lo[u]];
            fv2 xt; xt.x = xf[u]; xt.y = xf[u];
            x0v[u] = xt;
            fv2 ht; ht.x = hs; ht.y = hs;
            hsv[u] = ht;
            fv2 dt; dt.x = hd; dt.y = hd;
            hdv[u] = dt;
            o2[u] = ZERO2;
        }
        #pragma unroll 4
        for (int j = 0; j < 64; j += 2) {
            fv2 aj = *reinterpret_cast<const fv2*>(W1 + j);
            fv2 bj = *reinterpret_cast<const fv2*>(W1 + 64 + j);
            fv2 cj = *reinterpret_cast<const fv2*>(W1 + 128 + j);
            fv2 dj = *reinterpret_cast<const fv2*>(B1 + j);
            fv2 vj = *reinterpret_cast<const fv2*>(W2 + j);
            #pragma unroll
            for (int u = 0; u < 4; ++u) {
                fv2 t = FMA2(x0v[u], aj,
                         FMA2(hsv[u], bj, FMA2(hdv[u], cj, dj)));
                t = MAX2(t, ZERO2);
                o2[u] = FMA2(t, vj, o2[u]);
            }
        }
        #pragma unroll
        for (int u = 0; u < 4; ++u) {
            int j = i + u * T;
            if (j < i1) {
                float eh = fmaxf(o2[u].x + o2[u].y + b2, 0.f);
                float ex = __expf(eh);
                payF[2 * j + 1] = ex;   // e2 -> payA[j].y (dist dead)
                atomicAdd(&lagg[lo[u]], eh);
                atomicAdd(&ls2[lo[u]], ex);
            }
        }
        i = inext;
        #pragma unroll
        for (int u = 0; u < 4; ++u) { pa[u] = pb[u]; xf[u] = xg[u]; }
    }
    __syncthreads();
    size_t po = (size_t)blockIdx.x << shift;
    for (int t = threadIdx.x; t < bw; t += blockDim.x) {
        pAgg[po + t] = lagg[t];
        pS2[po + t] = ls2[t];
    }
}

// finB: sum partials; H2 = nuMLP(agg, h1); S2
__global__ void __launch_bounds__(256) k_finB(
    const float* __restrict__ pAgg, const float* __restrict__ pS2,
    const float* __restrict__ H1,
    const float* __restrict__ NW1, const float* __restrict__ NB1,
    const float* __restrict__ NW2, const float* __restrict__ NB2,
    float* __restrict__ H2, float* __restrict__ S2, int shift, int n, int G)
{
    int d = blockIdx.x * blockDim.x + threadIdx.x;
    if (d >= n) return;
    int c = d >> shift, t = d & ((1 << shift) - 1);
    size_t b = (size_t)c * G << shift;
    int bw = 1 << shift;
    float agg = 0.f, s2 = 0.f;
    for (int g = 0; g < G; ++g) {
        agg += pAgg[b + (size_t)g * bw + t];
        s2  += pS2[b + (size_t)g * bw + t];
    }
    float xh = H1[d];
    float o = NB2[0];
    #pragma unroll 4
    for (int j = 0; j < 64; ++j) {
        float a = fmaf(agg, NW1[j], fmaf(xh, NW1[64 + j], NB1[j]));
        o = fmaf(fmaxf(a, 0.f), NW2[j], o);
    }
    H2[d] = fmaxf(o, 0.f);
    S2[d] = s2;
}

// passC main: partial num2. Single contiguous stream: payA[j] = (sd, e2).
__global__ void __launch_bounds__(256) k_passC(
    const float2* __restrict__ payA,
    const float* __restrict__ H2, const int* __restrict__ base,
    float* __restrict__ pNum, int shift, int G)
{
    __shared__ float lnum[512];
    int c = blockIdx.x / G, g = blockIdx.x % G;
    int bw = 1 << shift, mask = bw - 1;
    for (int t = threadIdx.x; t < bw; t += blockDim.x) lnum[t] = 0.f;
    __syncthreads();
    int b0 = base[c], len = base[c + 1] - b0;
    int i0 = b0 + (int)(((long long)len * g) / G);
    int i1 = b0 + (int)(((long long)len * (g + 1)) / G);
    const int T = blockDim.x;
    for (int i = i0 + (int)threadIdx.x; i < i1; i += 4 * T) {
        fv2 p[4]; bool v[4]; int sd[4]; float h[4];
        #pragma unroll
        for (int u = 0; u < 4; ++u) {
            int j = i + u * T;
            v[u] = j < i1;
            p[u].x = 0.f; p[u].y = 0.f;
            if (v[u]) p[u] = __builtin_nontemporal_load(
                          reinterpret_cast<const fv2*>(payA) + j);
        }
        #pragma unroll
        for (int u = 0; u < 4; ++u) {
            sd[u] = __float_as_int(p[u].x);
            h[u] = v[u] ? H2[sd[u] >> shift] : 0.f;
        }
        #pragma unroll
        for (int u = 0; u < 4; ++u) {
            if (v[u]) atomicAdd(&lnum[sd[u] & mask], p[u].y * h[u]);
        }
    }
    __syncthreads();
    size_t po = (size_t)blockIdx.x << shift;
    for (int t = threadIdx.x; t < bw; t += blockDim.x)
        pNum[po + t] = lnum[t];
}

// finC: sum partials; OUT = decMLP(num2/s2)
__global__ void __launch_bounds__(256) k_finC(
    const float* __restrict__ pNum, const float* __restrict__ S2,
    const float* __restrict__ W1, const float* __restrict__ B1,
    const float* __restrict__ W2, const float* __restrict__ B2,
    float* __restrict__ OUT, int shift, int n, int G)
{
    int d = blockIdx.x * blockDim.x + threadIdx.x;
    if (d >= n) return;
    int c = d >> shift, t = d & ((1 << shift) - 1);
    size_t b = (size_t)c * G << shift;
    int bw = 1 << shift;
    float m = 0.f;
    for (int g = 0; g < G; ++g) m += pNum[b + (size_t)g * bw + t];
    float s = S2[d];
    float x = (s != 0.f) ? m / s : 0.f;
    float o = B2[0];
    #pragma unroll 4
    for (int j = 0; j < 64; ++j) {
        float a = fmaf(x, W1[j], B1[j]);
        o = fmaf(fmaxf(a, 0.f), W2[j], o);
    }
    OUT[d] = fmaxf(o, 0.f);
}

// ===================== fallback (atomic path) ==============================

__device__ __forceinline__ void atomAddF(float* p, float v) { unsafeAtomicAdd(p, v); }

__global__ void k_zero(float* __restrict__ p, int n) {
    int i = blockIdx.x * blockDim.x + threadIdx.x;
    if (i < n) p[i] = 0.f;
}

__global__ void __launch_bounds__(256) k_agg1(
    const float* __restrict__ DIST, const int* __restrict__ SRC,
    const int* __restrict__ DST, const float* __restrict__ H0,
    float* __restrict__ S1, float* __restrict__ NUM1, int e)
{
    int i = blockIdx.x * blockDim.x + threadIdx.x;
    if (i >= e) return;
    float ev = __expf(DIST[i]);
    atomAddF(&S1[DST[i]], ev);
    atomAddF(&NUM1[DST[i]], ev * H0[SRC[i]]);
}

__global__ void k_div(const float* __restrict__ NUM, const float* __restrict__ S,
                      float* __restrict__ H, int n) {
    int i = blockIdx.x * blockDim.x + threadIdx.x;
    if (i < n) {
        float s = S[i];
        H[i] = (s != 0.f) ? NUM[i] / s : 0.f;
    }
}

__global__ void __launch_bounds__(256) k_edgeF(
    const float* __restrict__ EF, const int* __restrict__ SRC,
    const int* __restrict__ DST, const float* __restrict__ H1,
    const float* __restrict__ W1, const float* __restrict__ B1,
    const float* __restrict__ W2, const float* __restrict__ B2,
    float* __restrict__ E2, float* __restrict__ AGG, float* __restrict__ S2, int e)
{
    int i = blockIdx.x * blockDim.x + threadIdx.x;
    if (i >= e) return;
    float x0 = EF[i];
    int s = SRC[i], d = DST[i];
    float h_s = H1[s], h_d = H1[d];
    float o = B2[0];
    for (int j = 0; j < 64; ++j) {
        float aj = fmaf(x0, W1[j], fmaf(h_s, W1[64+j], fmaf(h_d, W1[128+j], B1[j])));
        o = fmaf(fmaxf(aj, 0.f), W2[j], o);
    }
    float eh = fmaxf(o, 0.f);
    float ex = __expf(eh);
    E2[i] = ex;
    atomAddF(&AGG[d], eh);
    atomAddF(&S2[d], ex);
}

__global__ void k_nu(const float* __restrict__ AGG, const float* __restrict__ H1,
                     const float* __restrict__ W1, const float* __restrict__ B1,
                     const float* __restrict__ W2, const float* __restrict__ B2,
                     float* __restrict__ H2, int n)
{
    int i = blockIdx.x * blockDim.x + threadIdx.x;
    if (i >= n) return;
    float x0 = AGG[i], x1 = H1[i];
    float o = B2[0];
    #pragma unroll
    for (int j = 0; j < 64; ++j) {
        float a = fmaf(x0, W1[j], fmaf(x1, W1[64 + j], B1[j]));
        o = fmaf(fmaxf(a, 0.f), W2[j], o);
    }
    H2[i] = fmaxf(o, 0.f);
}

__global__ void __launch_bounds__(256) k_agg2F(
    const float* __restrict__ E2, const int* __restrict__ SRC,
    const int* __restrict__ DST, const float* __restrict__ H2,
    float* __restrict__ NUM2, int e)
{
    int i = blockIdx.x * blockDim.x + threadIdx.x;
    if (i >= e) return;
    atomAddF(&NUM2[DST[i]], E2[i] * H2[SRC[i]]);
}

__global__ void k_final(const float* __restrict__ NUM2, const float* __restrict__ S2,
                        const float* __restrict__ W1, const float* __restrict__ B1,
                        const float* __restrict__ W2, const float* __restrict__ B2,
                        float* __restrict__ OUT, int n)
{
    int i = blockIdx.x * blockDim.x + threadIdx.x;
    if (i >= n) return;
    float s = S2[i];
    float x = (s != 0.f) ? NUM2[i] / s : 0.f;
    float o = B2[0];
    #pragma unroll
    for (int j = 0; j < 64; ++j) {
        float a = fmaf(x, W1[j], B1[j]);
        o = fmaf(fmaxf(a, 0.f), W2[j], o);
    }
    OUT[i] = fmaxf(o, 0.f);
}

// ============================ launch =======================================

extern "C" void kernel_launch(void* const* d_in, const int* in_sizes, int n_in,
                              void* d_out, int out_size, void* d_ws, size_t ws_size,
                              hipStream_t stream)
{
    const float* node_feat = (const float*)d_in[0];
    const float* edge_feat = (const float*)d_in[1];
    const float* edge_dist = (const float*)d_in[2];
    const int*   src       = (const int*)d_in[3];
    const int*   dst       = (const int*)d_in[4];
    const float* enc_w1 = (const float*)d_in[5];
    const float* enc_b1 = (const float*)d_in[6];
    const float* enc_w2 = (const float*)d_in[7];
    const float* enc_b2 = (const float*)d_in[8];
    const float* nu_w1  = (const float*)d_in[9];
    const float* nu_b1  = (const float*)d_in[10];
    const float* nu_w2  = (const float*)d_in[11];
    const float* nu_b2  = (const float*)d_in[12];
    const float* eu_w1  = (const float*)d_in[13];
    const float* eu_b1  = (const float*)d_in[14];
    const float* eu_w2  = (const float*)d_in[15];
    const float* eu_b2  = (const float*)d_in[16];
    const float* dec_w1 = (const float*)d_in[17];
    const float* dec_b1 = (const float*)d_in[18];
    const float* dec_w2 = (const float*)d_in[19];
    const float* dec_b2 = (const float*)d_in[20];

    const int n = in_sizes[0] / 128;
    const int e = in_sizes[1];
    const int B = 256;

    // shift=9: scatter-side optimum (r14: shift=8 -> 335MB write-amp).
    int shift = 9;
    while ((((n + (1 << shift) - 1) >> shift) > 512) && shift < 12) shift++;
    const int nbkt = (n + (1 << shift) - 1) >> shift;
    int epb = (e + NHB - 1) / NHB;
    epb = (epb + 3) & ~3;

    // ws layout (4B words): h0,h1,h2,s2 [4n] | base[nbkt+1] bktCnt[nbkt]
    // hist[nbkt*NHB] | pad8 | payA[2e] | ef_s[e] | pP0 | pP1
    float* ws = (float*)d_ws;
    size_t w = (size_t)4 * n;
    int* base   = (int*)(ws + w); w += nbkt + 1;
    int* bktCnt = (int*)(ws + w); w += nbkt;
    int* hist   = (int*)(ws + w); w += (size_t)nbkt * NHB;
    w = (w + 1) & ~(size_t)1;
    float2* payA = (float2*)(ws + w); w += (size_t)2 * e;
    float* ef_s  = ws + w; w += e;

    // pick largest G in {16,8,4,2,1} whose partial arrays fit the workspace
    int G = 16;
    size_t psz;
    size_t need;
    for (;;) {
        psz = ((size_t)nbkt * G) << shift;
        need = (w + 2 * psz) * 4;
        if (need <= ws_size || G == 1) break;
        G >>= 1;
    }
    float* pP0 = ws + w;
    float* pP1 = ws + w + psz;

    float* h0 = ws;
    float* h1 = ws + (size_t)1 * n;
    float* h2 = ws + (size_t)2 * n;
    float* s2 = ws + (size_t)3 * n;

    if (ws_size >= need && nbkt <= 512 && (1 << shift) <= 512 &&
        ((size_t)n << shift) < (1u << 30)) {
        const int gE = nbkt * G;
        hipLaunchKernelGGL(k_chist, dim3(NHB), dim3(1024), 0, stream,
                           dst, hist, e, nbkt, shift, epb);
        hipLaunchKernelGGL(k_scanA, dim3(nbkt), dim3(B), 0, stream, hist, bktCnt);
        hipLaunchKernelGGL(k_scanB, dim3(1), dim3(B), 0, stream, bktCnt, base, nbkt, e);
        hipLaunchKernelGGL(k_scatter, dim3(NHB), dim3(1024), 0, stream,
                           dst, src, edge_dist, edge_feat, hist, base,
                           payA, ef_s, e, nbkt, shift, epb);
        hipLaunchKernelGGL(k_enc, dim3((n + B - 1) / B), dim3(B), 0, stream,
                           node_feat, enc_w1, enc_b1, enc_w2, enc_b2, h0, n);
        hipLaunchKernelGGL(k_passA, dim3(gE), dim3(B), 0, stream,
                           payA, h0, base, pP0, pP1, shift, G);
        hipLaunchKernelGGL(k_finA, dim3((n + B - 1) / B), dim3(B), 0, stream,
                           pP0, pP1, h1, shift, n, G);
        hipLaunchKernelGGL(k_passB, dim3(gE), dim3(B), 0, stream,
                           payA, ef_s, h1, eu_w1, eu_b1, eu_w2, eu_b2, base,
                           pP0, pP1, shift, n, G);
        hipLaunchKernelGGL(k_finB, dim3((n + B - 1) / B), dim3(B), 0, stream,
                           pP0, pP1, h1, nu_w1, nu_b1, nu_w2, nu_b2, h2, s2,
                           shift, n, G);
        hipLaunchKernelGGL(k_passC, dim3(gE), dim3(B), 0, stream,
                           payA, h2, base, pP0, shift, G);
        hipLaunchKernelGGL(k_finC, dim3((n + B - 1) / B), dim3(B), 0, stream,
                           pP0, s2, dec_w1, dec_b1, dec_w2, dec_b2,
                           (float*)d_out, shift, n, G);
    } else {
        // fallback: atomic path (needs 8n + e floats)
        float* agg  = ws + (size_t)2 * n;
        float* s1   = ws + (size_t)4 * n;
        float* num1 = ws + (size_t)5 * n;
        float* num2 = ws + (size_t)6 * n;
        float* h2f  = ws + (size_t)7 * n;
        float* e2   = ws + (size_t)8 * n;
        hipLaunchKernelGGL(k_zero, dim3((5 * n + B - 1) / B), dim3(B), 0, stream,
                           agg, 5 * n);
        hipLaunchKernelGGL(k_enc, dim3((n + B - 1) / B), dim3(B), 0, stream,
                           node_feat, enc_w1, enc_b1, enc_w2, enc_b2, h0, n);
        hipLaunchKernelGGL(k_agg1, dim3((e + B - 1) / B), dim3(B), 0, stream,
                           edge_dist, src, dst, h0, s1, num1, e);
        hipLaunchKernelGGL(k_div, dim3((n + B - 1) / B), dim3(B), 0, stream,
                           num1, s1, h1, n);
        hipLaunchKernelGGL(k_edgeF, dim3((e + B - 1) / B), dim3(B), 0, stream,
                           edge_feat, src, dst, h1, eu_w1, eu_b1, eu_w2, eu_b2,
                           e2, agg, s2, e);
        hipLaunchKernelGGL(k_nu, dim3((n + B - 1) / B), dim3(B), 0, stream,
                           agg, h1, nu_w1, nu_b1, nu_w2, nu_b2, h2f, n);
        hipLaunchKernelGGL(k_agg2F, dim3((e + B - 1) / B), dim3(B), 0, stream,
                           e2, src, dst, h2f, num2, e);
        hipLaunchKernelGGL(k_final, dim3((n + B - 1) / B), dim3(B), 0, stream,
                           num2, s2, dec_w1, dec_b1, dec_w2, dec_b2, (float*)d_out, n);
    }
}